// Round 1
// baseline (2724.290 us; speedup 1.0000x reference)
//
#include <hip/hip_runtime.h>
#include <hip/hip_bf16.h>
#include <math.h>

#define USER_NUM 100000
#define ITEM_NUM 50000
#define N_NODES  150000
#define N_EDGES  2400000
#define OUT_DIM  64
#define HID_DIM  128
#define BATCH    4096
#define EPS_BN   1e-5f

// ---------------- preprocessing ----------------

__global__ __launch_bounds__(256) void zero_int_kernel(int* __restrict__ p, int n) {
    int i = blockIdx.x * 256 + threadIdx.x;
    if (i < n) p[i] = 0;
}

__global__ __launch_bounds__(256) void count_kernel(const int* __restrict__ dst, int* __restrict__ cnt) {
    int i = blockIdx.x * 256 + threadIdx.x;
    if (i < N_EDGES) atomicAdd(&cnt[dst[i]], 1);
}

__global__ __launch_bounds__(256) void dis_kernel(const int* __restrict__ cnt, float* __restrict__ dis) {
    int i = blockIdx.x * 256 + threadIdx.x;
    if (i < N_NODES) dis[i] = rsqrtf(1.0f + (float)cnt[i]);
}

#define SCAN_T 1024
#define SCAN_V 16
__global__ __launch_bounds__(SCAN_T) void scan_kernel(const int* __restrict__ cnt,
                                                      int* __restrict__ off,
                                                      int* __restrict__ cur, int n) {
    __shared__ int lds[SCAN_T];
    __shared__ int carry;
    int tid = threadIdx.x;
    if (tid == 0) carry = 0;
    __syncthreads();
    for (int base = 0; base < n; base += SCAN_T * SCAN_V) {
        int idx0 = base + tid * SCAN_V;
        int loc[SCAN_V];
        int tot = 0;
#pragma unroll
        for (int j = 0; j < SCAN_V; j++) {
            int i = idx0 + j;
            int v = (i < n) ? cnt[i] : 0;
            loc[j] = tot;           // exclusive within thread
            tot += v;
        }
        lds[tid] = tot;
        __syncthreads();
        // Hillis-Steele inclusive scan over SCAN_T
        for (int d = 1; d < SCAN_T; d <<= 1) {
            int t = (tid >= d) ? lds[tid - d] : 0;
            __syncthreads();
            lds[tid] += t;
            __syncthreads();
        }
        int excl = carry + lds[tid] - tot;
#pragma unroll
        for (int j = 0; j < SCAN_V; j++) {
            int i = idx0 + j;
            if (i < n) { off[i] = excl + loc[j]; cur[i] = excl + loc[j]; }
        }
        __syncthreads();
        if (tid == 0) carry += lds[SCAN_T - 1];
        __syncthreads();
    }
    if (tid == 0) off[n] = carry;
}

__global__ __launch_bounds__(256) void fill_kernel(const int* __restrict__ src, const int* __restrict__ dst,
                                                   int* __restrict__ cursor, int* __restrict__ csr_src) {
    int i = blockIdx.x * 256 + threadIdx.x;
    if (i < N_EDGES) {
        int d = dst[i];
        int p = atomicAdd(&cursor[d], 1);
        csr_src[p] = src[i];
    }
}

// ---------------- GEMM: out[row][col] = sum_k x[row][k] * W[k][col] ----------------
// block = 256 threads; GROUPS = 256/DOUT row-groups; each handles RPT rows.

template<int DIN, int DOUT, int RPT>
__global__ __launch_bounds__(256) void gemm_kernel(const float* __restrict__ xlo,
                                                   const float* __restrict__ xhi, int split,
                                                   const float* __restrict__ W,
                                                   float* __restrict__ out, int nrows) {
    __shared__ float Wl[DIN * DOUT];
    const int tid = threadIdx.x;
    for (int i = tid; i < DIN * DOUT; i += 256) Wl[i] = W[i];
    __syncthreads();
    const int GROUPS = 256 / DOUT;
    int col  = tid % DOUT;
    int rg   = tid / DOUT;
    int row0 = (blockIdx.x * GROUPS + rg) * RPT;

    const float* xr[RPT];
#pragma unroll
    for (int r = 0; r < RPT; r++) {
        int row = row0 + r;
        if (row > nrows - 1) row = nrows - 1;   // clamp for safe (discarded) loads
        xr[r] = (row < split) ? xlo + (size_t)row * DIN
                              : xhi + (size_t)(row - split) * DIN;
    }
    float acc[RPT];
#pragma unroll
    for (int r = 0; r < RPT; r++) acc[r] = 0.f;

    for (int k = 0; k < DIN; k += 4) {
        float w0 = Wl[(k + 0) * DOUT + col];
        float w1 = Wl[(k + 1) * DOUT + col];
        float w2 = Wl[(k + 2) * DOUT + col];
        float w3 = Wl[(k + 3) * DOUT + col];
#pragma unroll
        for (int r = 0; r < RPT; r++) {
            float4 xv = *(const float4*)(xr[r] + k);
            acc[r] = fmaf(xv.x, w0, fmaf(xv.y, w1, fmaf(xv.z, w2, fmaf(xv.w, w3, acc[r]))));
        }
    }
#pragma unroll
    for (int r = 0; r < RPT; r++) {
        int row = row0 + r;
        if (row < nrows) out[(size_t)row * DOUT + col] = acc[r];
    }
}

// ---------------- edge aggregation (CSR gather, one wave per node) ----------------
// out[i] = sum_{e: dst=i} h[src_e]*dis[src_e]*dis[i] + h[i]*dis[i]^2 + bias

template<int DOUT>
__global__ __launch_bounds__(256) void agg_kernel(const float* __restrict__ h,
                                                  const float* __restrict__ dis,
                                                  const int* __restrict__ off,
                                                  const int* __restrict__ csr_src,
                                                  const float* __restrict__ bias,
                                                  float* __restrict__ out, int n) {
    int wave = threadIdx.x >> 6;
    int lane = threadIdx.x & 63;
    int node = blockIdx.x * 4 + wave;
    if (node >= n) return;
    float di  = dis[node];
    int   beg = off[node], end = off[node + 1];
    if (DOUT == 128) {
        float ax = 0.f, ay = 0.f;
        for (int e = beg; e < end; e++) {
            int   s  = csr_src[e];
            float ns = dis[s] * di;
            float2 hv = *(const float2*)(h + (size_t)s * 128 + lane * 2);
            ax = fmaf(hv.x, ns, ax);
            ay = fmaf(hv.y, ns, ay);
        }
        float2 hs = *(const float2*)(h + (size_t)node * 128 + lane * 2);
        float2 bb = *(const float2*)(bias + lane * 2);
        float dd = di * di;
        out[(size_t)node * 128 + lane * 2 + 0] = ax + hs.x * dd + bb.x;
        out[(size_t)node * 128 + lane * 2 + 1] = ay + hs.y * dd + bb.y;
    } else {
        float ax = 0.f;
        for (int e = beg; e < end; e++) {
            int   s  = csr_src[e];
            float ns = dis[s] * di;
            ax = fmaf(h[(size_t)s * 64 + lane], ns, ax);
        }
        float hs = h[(size_t)node * 64 + lane];
        out[(size_t)node * 64 + lane] = ax + hs * di * di + bias[lane];
    }
}

// ---------------- BN stats (two-stage, double partials) ----------------

__global__ __launch_bounds__(128) void stats1_kernel(const float* __restrict__ x,
                                                     double* __restrict__ part) {
    int col = threadIdx.x;
    double a = 0.0, b = 0.0;
    for (int row = blockIdx.x; row < N_NODES; row += gridDim.x) {
        float v = x[(size_t)row * HID_DIM + col];
        a += v;
        b += (double)v * (double)v;
    }
    part[(size_t)blockIdx.x * 256 + col]       = a;
    part[(size_t)blockIdx.x * 256 + 128 + col] = b;
}

__global__ __launch_bounds__(128) void stats2_kernel(const double* __restrict__ part, int npart,
                                                     const float* __restrict__ g,
                                                     const float* __restrict__ beta,
                                                     float* __restrict__ a_out,
                                                     float* __restrict__ b_out) {
    int col = threadIdx.x;
    double s1 = 0.0, s2 = 0.0;
    for (int p = 0; p < npart; p++) {
        s1 += part[(size_t)p * 256 + col];
        s2 += part[(size_t)p * 256 + 128 + col];
    }
    double mean = s1 / (double)N_NODES;
    double var  = s2 / (double)N_NODES - mean * mean;
    float inv = rsqrtf((float)var + EPS_BN);
    float aa  = g[col] * inv;
    a_out[col] = aa;
    b_out[col] = beta[col] - (float)mean * aa;
}

// ---------------- fused BN-apply + ReLU + row L2-norm (wave per row) ----------------

__global__ __launch_bounds__(256) void bn_relu_l2_kernel(const float* __restrict__ in,
                                                         const float* __restrict__ a,
                                                         const float* __restrict__ b,
                                                         float* __restrict__ outp, int n) {
    int wave = threadIdx.x >> 6;
    int lane = threadIdx.x & 63;
    int row  = blockIdx.x * 4 + wave;
    if (row >= n) return;
    float2 v  = *(const float2*)(in + (size_t)row * 128 + lane * 2);
    float2 aa = *(const float2*)(a + lane * 2);
    float2 bb = *(const float2*)(b + lane * 2);
    float y0 = fmaxf(fmaf(v.x, aa.x, bb.x), 0.f);
    float y1 = fmaxf(fmaf(v.y, aa.y, bb.y), 0.f);
    float ss = y0 * y0 + y1 * y1;
#pragma unroll
    for (int d = 32; d >= 1; d >>= 1) ss += __shfl_xor(ss, d);
    float nn  = sqrtf(ss);
    float inv = 1.f / fmaxf(nn, 1e-12f);
    outp[(size_t)row * 128 + lane * 2 + 0] = y0 * inv;
    outp[(size_t)row * 128 + lane * 2 + 1] = y1 * inv;
}

// ---------------- loss ----------------

__global__ void zero_float_kernel(float* p) { *p = 0.f; }

__global__ __launch_bounds__(256) void loss_kernel(const float* __restrict__ X,
                                                   const int* __restrict__ uid,
                                                   const int* __restrict__ pid,
                                                   const int* __restrict__ nid,
                                                   float* __restrict__ out0) {
    int wave = threadIdx.x >> 6;
    int lane = threadIdx.x & 63;
    int b = blockIdx.x * 4 + wave;
    if (b >= BATCH) return;
    const float* u = X + (size_t)uid[b] * OUT_DIM;
    const float* p = X + (size_t)(USER_NUM + pid[b]) * OUT_DIM;
    const float* q = X + (size_t)(USER_NUM + nid[b]) * OUT_DIM;
    float uv = u[lane];
    float ps = uv * p[lane];
    float ns = uv * q[lane];
#pragma unroll
    for (int d = 32; d >= 1; d >>= 1) {
        ps += __shfl_xor(ps, d);
        ns += __shfl_xor(ns, d);
    }
    if (lane == 0) {
        float t  = ns - ps;                                   // -(pos - neg)
        float sp = fmaxf(t, 0.f) + log1pf(expf(-fabsf(t)));   // softplus(t)
        atomicAdd(out0, sp * (1.0f / BATCH));
    }
}

// ---------------- launch ----------------

extern "C" void kernel_launch(void* const* d_in, const int* in_sizes, int n_in,
                              void* d_out, int out_size, void* d_ws, size_t ws_size,
                              hipStream_t stream) {
    const float* user_emb = (const float*)d_in[0];
    const float* item_emb = (const float*)d_in[1];
    const float* W0  = (const float*)d_in[2];
    const float* b0  = (const float*)d_in[3];
    const float* g0  = (const float*)d_in[4];
    const float* be0 = (const float*)d_in[5];
    const float* W1  = (const float*)d_in[6];
    const float* b1  = (const float*)d_in[7];
    const float* g1  = (const float*)d_in[8];
    const float* be1 = (const float*)d_in[9];
    const float* W2  = (const float*)d_in[10];
    const float* b2  = (const float*)d_in[11];
    const int* user_id  = (const int*)d_in[12];
    const int* pos_item = (const int*)d_in[13];
    const int* neg_item = (const int*)d_in[14];
    const int* edge     = (const int*)d_in[15];
    const int* src = edge;
    const int* dst = edge + N_EDGES;

    char* w = (char*)d_ws;
    auto alloc = [&](size_t bytes) -> char* {
        char* r = w;
        w += (bytes + 255) / 256 * 256;
        return r;
    };
    int*    cnt  = (int*)alloc((size_t)N_NODES * 4);
    int*    off  = (int*)alloc((size_t)(N_NODES + 1) * 4);
    int*    cur  = (int*)alloc((size_t)N_NODES * 4);
    int*    csr  = (int*)alloc((size_t)N_EDGES * 4);
    float*  dis  = (float*)alloc((size_t)N_NODES * 4);
    double* part = (double*)alloc((size_t)1024 * 256 * 8);
    float*  bn_a = (float*)alloc(128 * 4);
    float*  bn_b = (float*)alloc(128 * 4);
    float*  hbuf = (float*)alloc((size_t)N_NODES * HID_DIM * 4);
    float*  xbuf = (float*)alloc((size_t)N_NODES * HID_DIM * 4);

    float* out = (float*)d_out;
    float* X   = out + 1;   // node embeddings region (150000 x 64)

    const int EB = (N_EDGES + 255) / 256;
    const int NB = (N_NODES + 255) / 256;
    const int AGGB = (N_NODES + 3) / 4;

    // preprocessing: degree, dis, CSR
    zero_int_kernel<<<NB, 256, 0, stream>>>(cnt, N_NODES);
    count_kernel<<<EB, 256, 0, stream>>>(dst, cnt);
    dis_kernel<<<NB, 256, 0, stream>>>(cnt, dis);
    scan_kernel<<<1, SCAN_T, 0, stream>>>(cnt, off, cur, N_NODES);
    fill_kernel<<<EB, 256, 0, stream>>>(src, dst, cur, csr);

    // layer 0: (150000x64) @ (64x128)
    gemm_kernel<64, 128, 16><<<(N_NODES + 31) / 32, 256, 0, stream>>>(
        user_emb, item_emb, USER_NUM, W0, hbuf, N_NODES);
    agg_kernel<128><<<AGGB, 256, 0, stream>>>(hbuf, dis, off, csr, b0, xbuf, N_NODES);
    stats1_kernel<<<1024, 128, 0, stream>>>(xbuf, part);
    stats2_kernel<<<1, 128, 0, stream>>>(part, 1024, g0, be0, bn_a, bn_b);
    bn_relu_l2_kernel<<<AGGB, 256, 0, stream>>>(xbuf, bn_a, bn_b, xbuf, N_NODES);

    // layer 1: (150000x128) @ (128x128)
    gemm_kernel<128, 128, 16><<<(N_NODES + 31) / 32, 256, 0, stream>>>(
        xbuf, xbuf, N_NODES, W1, hbuf, N_NODES);
    agg_kernel<128><<<AGGB, 256, 0, stream>>>(hbuf, dis, off, csr, b1, xbuf, N_NODES);
    stats1_kernel<<<1024, 128, 0, stream>>>(xbuf, part);
    stats2_kernel<<<1, 128, 0, stream>>>(part, 1024, g1, be1, bn_a, bn_b);
    bn_relu_l2_kernel<<<AGGB, 256, 0, stream>>>(xbuf, bn_a, bn_b, xbuf, N_NODES);

    // layer 2: (150000x128) @ (128x64), output straight into d_out[1:]
    gemm_kernel<128, 64, 16><<<(N_NODES + 63) / 64, 256, 0, stream>>>(
        xbuf, xbuf, N_NODES, W2, hbuf, N_NODES);
    agg_kernel<64><<<AGGB, 256, 0, stream>>>(hbuf, dis, off, csr, b2, X, N_NODES);

    // loss
    zero_float_kernel<<<1, 1, 0, stream>>>(out);
    loss_kernel<<<(BATCH + 3) / 4, 256, 0, stream>>>(X, user_id, pos_item, neg_item, out);
}

// Round 4
// 1581.846 us; speedup vs baseline: 1.7222x; 1.7222x over previous
//
#include <hip/hip_runtime.h>
#include <hip/hip_bf16.h>
#include <math.h>

#define USER_NUM 100000
#define ITEM_NUM 50000
#define N_NODES  150000
#define N_EDGES  2400000
#define OUT_DIM  64
#define HID_DIM  128
#define BATCH    4096
#define EPS_BN   1e-5f

// ---------------- preprocessing ----------------

__global__ __launch_bounds__(256) void zero_int_kernel(int* __restrict__ p, int n) {
    int i = blockIdx.x * 256 + threadIdx.x;
    if (i < n) p[i] = 0;
}

__global__ __launch_bounds__(256) void count_kernel(const int* __restrict__ dst, int* __restrict__ cnt) {
    int i = blockIdx.x * 256 + threadIdx.x;
    if (i < N_EDGES) atomicAdd(&cnt[dst[i]], 1);
}

__global__ __launch_bounds__(256) void dis_kernel(const int* __restrict__ cnt, float* __restrict__ dis) {
    int i = blockIdx.x * 256 + threadIdx.x;
    if (i < N_NODES) dis[i] = rsqrtf(1.0f + (float)cnt[i]);
}

// 3-pass scan: per-block sums -> scan of block sums -> emit offsets
#define SC_ELEM 1024
#define SC_NB   ((N_NODES + SC_ELEM - 1) / SC_ELEM)   // 147

__global__ __launch_bounds__(256) void scan_part_kernel(const int* __restrict__ cnt,
                                                        int* __restrict__ psum) {
    __shared__ int red[4];
    int tid = threadIdx.x;
    int base = blockIdx.x * SC_ELEM + tid * 4;
    int s = 0;
#pragma unroll
    for (int j = 0; j < 4; j++) { int i = base + j; if (i < N_NODES) s += cnt[i]; }
#pragma unroll
    for (int d = 1; d < 64; d <<= 1) s += __shfl_xor(s, d);
    if ((tid & 63) == 0) red[tid >> 6] = s;
    __syncthreads();
    if (tid == 0) psum[blockIdx.x] = red[0] + red[1] + red[2] + red[3];
}

__global__ __launch_bounds__(256) void scan_mid_kernel(int* __restrict__ psum,
                                                       int* __restrict__ off, int nb) {
    __shared__ int lds[256];
    int tid = threadIdx.x;
    int v = (tid < nb) ? psum[tid] : 0;
    lds[tid] = v;
    __syncthreads();
    for (int d = 1; d < 256; d <<= 1) {
        int t = (tid >= d) ? lds[tid - d] : 0;
        __syncthreads();
        lds[tid] += t;
        __syncthreads();
    }
    if (tid < nb) psum[tid] = lds[tid] - v;   // exclusive
    if (tid == 0) off[N_NODES] = lds[255];
}

__global__ __launch_bounds__(256) void scan_emit_kernel(const int* __restrict__ cnt,
                                                        const int* __restrict__ psum,
                                                        int* __restrict__ off,
                                                        int* __restrict__ cur) {
    __shared__ int lds[256];
    int tid = threadIdx.x;
    int base = blockIdx.x * SC_ELEM + tid * 4;
    int v[4]; int s = 0;
#pragma unroll
    for (int j = 0; j < 4; j++) {
        int i = base + j;
        v[j] = (i < N_NODES) ? cnt[i] : 0;
        s += v[j];
    }
    lds[tid] = s;
    __syncthreads();
    for (int d = 1; d < 256; d <<= 1) {
        int t = (tid >= d) ? lds[tid - d] : 0;
        __syncthreads();
        lds[tid] += t;
        __syncthreads();
    }
    int run = psum[blockIdx.x] + lds[tid] - s;
#pragma unroll
    for (int j = 0; j < 4; j++) {
        int i = base + j;
        if (i < N_NODES) { off[i] = run; cur[i] = run; }
        run += v[j];
    }
}

__global__ __launch_bounds__(256) void fill_kernel(const int* __restrict__ src, const int* __restrict__ dst,
                                                   const float* __restrict__ dis,
                                                   int* __restrict__ cursor,
                                                   int* __restrict__ csr_src,
                                                   float* __restrict__ wgt) {
    int i = blockIdx.x * 256 + threadIdx.x;
    if (i < N_EDGES) {
        int s = src[i];
        int d = dst[i];
        int p = atomicAdd(&cursor[d], 1);
        csr_src[p] = s;
        wgt[p] = dis[s] * dis[d];
    }
}

// ---------------- GEMM: out[M][DOUT] = x[M][DIN] @ W[DIN][DOUT] ----------------
// 256 threads, block tile MBLK x DOUT, micro-tile 8x8 per thread,
// K-chunks of 32 staged in LDS with reg-staged prefetch of next chunk.

template<int DIN, int DOUT, int MBLK>
__global__ __launch_bounds__(256) void gemm_kernel(const float* __restrict__ xlo,
                                                   const float* __restrict__ xhi, int split,
                                                   const float* __restrict__ W,
                                                   float* __restrict__ out, int nrows) {
    constexpr int KC    = 32;
    constexpr int NC    = DIN / KC;
    constexpr int XS_PT = MBLK / 32;      // float4 x-loads per thread per chunk
    constexpr int WS_PT = DOUT / 32;      // float4 w-loads per thread per chunk
    constexpr int NCOLG = DOUT / 8;

    __shared__ float xs[MBLK][KC + 1];    // +1 pad: conflict-free column reads
    __shared__ float ws[KC][DOUT];

    const int tid  = threadIdx.x;
    const int row0 = blockIdx.x * MBLK;
    const int colg = tid % NCOLG;
    const int rowg = tid / NCOLG;

    float4 xr[XS_PT], wr[WS_PT];

    auto load_chunk = [&](int kc) {
#pragma unroll
        for (int i = 0; i < XS_PT; i++) {
            int idx = i * 256 + tid;
            int m = idx >> 3, kq = idx & 7;
            int row = row0 + m; if (row > nrows - 1) row = nrows - 1;
            const float* rp = (row < split) ? xlo + (size_t)row * DIN
                                            : xhi + (size_t)(row - split) * DIN;
            xr[i] = *(const float4*)(rp + kc + kq * 4);
        }
#pragma unroll
        for (int i = 0; i < WS_PT; i++) {
            int idx = i * 256 + tid;
            int n4 = idx % (DOUT / 4), kk = idx / (DOUT / 4);
            wr[i] = *(const float4*)(W + (size_t)(kc + kk) * DOUT + n4 * 4);
        }
    };
    auto write_chunk = [&]() {
#pragma unroll
        for (int i = 0; i < XS_PT; i++) {
            int idx = i * 256 + tid;
            int m = idx >> 3, kq = idx & 7;
            xs[m][kq * 4 + 0] = xr[i].x;
            xs[m][kq * 4 + 1] = xr[i].y;
            xs[m][kq * 4 + 2] = xr[i].z;
            xs[m][kq * 4 + 3] = xr[i].w;
        }
#pragma unroll
        for (int i = 0; i < WS_PT; i++) {
            int idx = i * 256 + tid;
            int n4 = idx % (DOUT / 4), kk = idx / (DOUT / 4);
            *(float4*)&ws[kk][n4 * 4] = wr[i];
        }
    };

    float acc[8][8];
#pragma unroll
    for (int r = 0; r < 8; r++)
#pragma unroll
        for (int c = 0; c < 8; c++) acc[r][c] = 0.f;

    load_chunk(0);
    write_chunk();
    __syncthreads();

    for (int c = 0; c < NC; c++) {
        if (c + 1 < NC) load_chunk((c + 1) * KC);   // prefetch under compute
#pragma unroll 4
        for (int k = 0; k < KC; k++) {
            float4 wa = *(const float4*)&ws[k][colg * 8];
            float4 wb = *(const float4*)&ws[k][colg * 8 + 4];
            float xv[8];
#pragma unroll
            for (int r = 0; r < 8; r++) xv[r] = xs[rowg * 8 + r][k];
#pragma unroll
            for (int r = 0; r < 8; r++) {
                acc[r][0] = fmaf(xv[r], wa.x, acc[r][0]);
                acc[r][1] = fmaf(xv[r], wa.y, acc[r][1]);
                acc[r][2] = fmaf(xv[r], wa.z, acc[r][2]);
                acc[r][3] = fmaf(xv[r], wa.w, acc[r][3]);
                acc[r][4] = fmaf(xv[r], wb.x, acc[r][4]);
                acc[r][5] = fmaf(xv[r], wb.y, acc[r][5]);
                acc[r][6] = fmaf(xv[r], wb.z, acc[r][6]);
                acc[r][7] = fmaf(xv[r], wb.w, acc[r][7]);
            }
        }
        __syncthreads();
        if (c + 1 < NC) { write_chunk(); __syncthreads(); }
    }

#pragma unroll
    for (int r = 0; r < 8; r++) {
        int row = row0 + rowg * 8 + r;
        if (row < nrows) {
            float4 o0 = make_float4(acc[r][0], acc[r][1], acc[r][2], acc[r][3]);
            float4 o1 = make_float4(acc[r][4], acc[r][5], acc[r][6], acc[r][7]);
            *(float4*)&out[(size_t)row * DOUT + colg * 8]     = o0;
            *(float4*)&out[(size_t)row * DOUT + colg * 8 + 4] = o1;
        }
    }
}

// ---------------- edge aggregation (CSR gather, one wave per node) ----------------
// out[i] = sum_e wgt[e]*h[csr[e]] + h[i]*dis[i]^2 + bias

template<int DOUT>
__global__ __launch_bounds__(256) void agg_kernel(const float* __restrict__ h,
                                                  const float* __restrict__ dis,
                                                  const int* __restrict__ off,
                                                  const int* __restrict__ csr,
                                                  const float* __restrict__ wgt,
                                                  const float* __restrict__ bias,
                                                  float* __restrict__ out, int n) {
    int wave = threadIdx.x >> 6;
    int lane = threadIdx.x & 63;
    int node = blockIdx.x * 4 + wave;
    if (node >= n) return;
    float di  = dis[node];
    int   beg = off[node], end = off[node + 1];
    if (DOUT == 128) {
        const float2* hp = (const float2*)h;
        float ax = 0.f, ay = 0.f;
        int e = beg;
        for (; e + 4 <= end; e += 4) {
            int s0 = csr[e], s1 = csr[e + 1], s2 = csr[e + 2], s3 = csr[e + 3];
            float w0 = wgt[e], w1 = wgt[e + 1], w2 = wgt[e + 2], w3 = wgt[e + 3];
            float2 h0 = hp[(size_t)s0 * 64 + lane];
            float2 h1 = hp[(size_t)s1 * 64 + lane];
            float2 h2 = hp[(size_t)s2 * 64 + lane];
            float2 h3 = hp[(size_t)s3 * 64 + lane];
            ax = fmaf(h0.x, w0, ax); ay = fmaf(h0.y, w0, ay);
            ax = fmaf(h1.x, w1, ax); ay = fmaf(h1.y, w1, ay);
            ax = fmaf(h2.x, w2, ax); ay = fmaf(h2.y, w2, ay);
            ax = fmaf(h3.x, w3, ax); ay = fmaf(h3.y, w3, ay);
        }
        for (; e < end; e++) {
            int s = csr[e]; float wv = wgt[e];
            float2 hv = hp[(size_t)s * 64 + lane];
            ax = fmaf(hv.x, wv, ax); ay = fmaf(hv.y, wv, ay);
        }
        float2 hs = hp[(size_t)node * 64 + lane];
        float2 bb = ((const float2*)bias)[lane];
        float dd = di * di;
        float2 o;
        o.x = ax + hs.x * dd + bb.x;
        o.y = ay + hs.y * dd + bb.y;
        ((float2*)out)[(size_t)node * 64 + lane] = o;
    } else {
        float ax = 0.f;
        int e = beg;
        for (; e + 4 <= end; e += 4) {
            int s0 = csr[e], s1 = csr[e + 1], s2 = csr[e + 2], s3 = csr[e + 3];
            float w0 = wgt[e], w1 = wgt[e + 1], w2 = wgt[e + 2], w3 = wgt[e + 3];
            float h0 = h[(size_t)s0 * 64 + lane];
            float h1 = h[(size_t)s1 * 64 + lane];
            float h2 = h[(size_t)s2 * 64 + lane];
            float h3 = h[(size_t)s3 * 64 + lane];
            ax = fmaf(h0, w0, ax); ax = fmaf(h1, w1, ax);
            ax = fmaf(h2, w2, ax); ax = fmaf(h3, w3, ax);
        }
        for (; e < end; e++) ax = fmaf(h[(size_t)csr[e] * 64 + lane], wgt[e], ax);
        float hs = h[(size_t)node * 64 + lane];
        out[(size_t)node * 64 + lane] = ax + hs * di * di + bias[lane];
    }
}

// ---------------- BN stats (two-stage, double partials) ----------------

#define STATS_NB 512

__global__ __launch_bounds__(128) void stats1_kernel(const float* __restrict__ x,
                                                     double* __restrict__ part) {
    int col = threadIdx.x;
    double a = 0.0, b = 0.0;
    for (int row = blockIdx.x; row < N_NODES; row += STATS_NB) {
        float v = x[(size_t)row * HID_DIM + col];
        a += v;
        b += (double)v * (double)v;
    }
    part[(size_t)blockIdx.x * 256 + col]       = a;
    part[(size_t)blockIdx.x * 256 + 128 + col] = b;
}

__global__ __launch_bounds__(128) void stats2_kernel(const double* __restrict__ part, int npart,
                                                     const float* __restrict__ g,
                                                     const float* __restrict__ beta,
                                                     float* __restrict__ a_out,
                                                     float* __restrict__ b_out) {
    int col = threadIdx.x;
    double s1 = 0.0, s2 = 0.0;
    for (int p = 0; p < npart; p++) {
        s1 += part[(size_t)p * 256 + col];
        s2 += part[(size_t)p * 256 + 128 + col];
    }
    double mean = s1 / (double)N_NODES;
    double var  = s2 / (double)N_NODES - mean * mean;
    float inv = rsqrtf((float)var + EPS_BN);
    float aa  = g[col] * inv;
    a_out[col] = aa;
    b_out[col] = beta[col] - (float)mean * aa;
}

// ---------------- fused BN-apply + ReLU + row L2-norm (wave per row) ----------------

__global__ __launch_bounds__(256) void bn_relu_l2_kernel(const float* __restrict__ in,
                                                         const float* __restrict__ a,
                                                         const float* __restrict__ b,
                                                         float* __restrict__ outp, int n) {
    int wave = threadIdx.x >> 6;
    int lane = threadIdx.x & 63;
    int row  = blockIdx.x * 4 + wave;
    if (row >= n) return;
    float2 v  = *(const float2*)(in + (size_t)row * 128 + lane * 2);
    float2 aa = *(const float2*)(a + lane * 2);
    float2 bb = *(const float2*)(b + lane * 2);
    float y0 = fmaxf(fmaf(v.x, aa.x, bb.x), 0.f);
    float y1 = fmaxf(fmaf(v.y, aa.y, bb.y), 0.f);
    float ss = y0 * y0 + y1 * y1;
#pragma unroll
    for (int d = 32; d >= 1; d >>= 1) ss += __shfl_xor(ss, d);
    float nn  = sqrtf(ss);
    float inv = 1.f / fmaxf(nn, 1e-12f);
    outp[(size_t)row * 128 + lane * 2 + 0] = y0 * inv;
    outp[(size_t)row * 128 + lane * 2 + 1] = y1 * inv;
}

// ---------------- loss ----------------

__global__ void zero_float_kernel(float* p) { *p = 0.f; }

__global__ __launch_bounds__(256) void loss_kernel(const float* __restrict__ X,
                                                   const int* __restrict__ uid,
                                                   const int* __restrict__ pid,
                                                   const int* __restrict__ nid,
                                                   float* __restrict__ out0) {
    int wave = threadIdx.x >> 6;
    int lane = threadIdx.x & 63;
    int b = blockIdx.x * 4 + wave;
    if (b >= BATCH) return;
    const float* u = X + (size_t)uid[b] * OUT_DIM;
    const float* p = X + (size_t)(USER_NUM + pid[b]) * OUT_DIM;
    const float* q = X + (size_t)(USER_NUM + nid[b]) * OUT_DIM;
    float uv = u[lane];
    float ps = uv * p[lane];
    float ns = uv * q[lane];
#pragma unroll
    for (int d = 32; d >= 1; d >>= 1) {
        ps += __shfl_xor(ps, d);
        ns += __shfl_xor(ns, d);
    }
    if (lane == 0) {
        float t  = ns - ps;                                   // -(pos - neg)
        float sp = fmaxf(t, 0.f) + log1pf(expf(-fabsf(t)));   // softplus(t)
        atomicAdd(out0, sp * (1.0f / BATCH));
    }
}

// ---------------- launch ----------------

extern "C" void kernel_launch(void* const* d_in, const int* in_sizes, int n_in,
                              void* d_out, int out_size, void* d_ws, size_t ws_size,
                              hipStream_t stream) {
    const float* user_emb = (const float*)d_in[0];
    const float* item_emb = (const float*)d_in[1];
    const float* W0  = (const float*)d_in[2];
    const float* b0  = (const float*)d_in[3];
    const float* g0  = (const float*)d_in[4];
    const float* be0 = (const float*)d_in[5];
    const float* W1  = (const float*)d_in[6];
    const float* b1  = (const float*)d_in[7];
    const float* g1  = (const float*)d_in[8];
    const float* be1 = (const float*)d_in[9];
    const float* W2  = (const float*)d_in[10];
    const float* b2  = (const float*)d_in[11];
    const int* user_id  = (const int*)d_in[12];
    const int* pos_item = (const int*)d_in[13];
    const int* neg_item = (const int*)d_in[14];
    const int* edge     = (const int*)d_in[15];
    const int* src = edge;
    const int* dst = edge + N_EDGES;

    char* w = (char*)d_ws;
    auto alloc = [&](size_t bytes) -> char* {
        char* r = w;
        w += (bytes + 255) / 256 * 256;
        return r;
    };
    int*    cnt  = (int*)alloc((size_t)N_NODES * 4);
    int*    off  = (int*)alloc((size_t)(N_NODES + 1) * 4);
    int*    cur  = (int*)alloc((size_t)N_NODES * 4);
    int*    csr  = (int*)alloc((size_t)N_EDGES * 4);
    float*  wgt  = (float*)alloc((size_t)N_EDGES * 4);
    float*  dis  = (float*)alloc((size_t)N_NODES * 4);
    int*    psum = (int*)alloc((size_t)SC_NB * 4);
    double* part = (double*)alloc((size_t)STATS_NB * 256 * 8);
    float*  bn_a = (float*)alloc(128 * 4);
    float*  bn_b = (float*)alloc(128 * 4);
    float*  hbuf = (float*)alloc((size_t)N_NODES * HID_DIM * 4);
    float*  xbuf = (float*)alloc((size_t)N_NODES * HID_DIM * 4);

    float* out = (float*)d_out;
    float* X   = out + 1;   // node embeddings region (150000 x 64)

    const int EB = (N_EDGES + 255) / 256;
    const int NB = (N_NODES + 255) / 256;
    const int AGGB = (N_NODES + 3) / 4;

    // preprocessing: degree, dis, CSR (+ per-edge weights)
    zero_int_kernel<<<NB, 256, 0, stream>>>(cnt, N_NODES);
    count_kernel<<<EB, 256, 0, stream>>>(dst, cnt);
    dis_kernel<<<NB, 256, 0, stream>>>(cnt, dis);
    scan_part_kernel<<<SC_NB, 256, 0, stream>>>(cnt, psum);
    scan_mid_kernel<<<1, 256, 0, stream>>>(psum, off, SC_NB);
    scan_emit_kernel<<<SC_NB, 256, 0, stream>>>(cnt, psum, off, cur);
    fill_kernel<<<EB, 256, 0, stream>>>(src, dst, dis, cur, csr, wgt);

    // layer 0: (150000x64) @ (64x128)
    gemm_kernel<64, 128, 128><<<(N_NODES + 127) / 128, 256, 0, stream>>>(
        user_emb, item_emb, USER_NUM, W0, hbuf, N_NODES);
    agg_kernel<128><<<AGGB, 256, 0, stream>>>(hbuf, dis, off, csr, wgt, b0, xbuf, N_NODES);
    stats1_kernel<<<STATS_NB, 128, 0, stream>>>(xbuf, part);
    stats2_kernel<<<1, 128, 0, stream>>>(part, STATS_NB, g0, be0, bn_a, bn_b);
    bn_relu_l2_kernel<<<AGGB, 256, 0, stream>>>(xbuf, bn_a, bn_b, xbuf, N_NODES);

    // layer 1: (150000x128) @ (128x128)
    gemm_kernel<128, 128, 128><<<(N_NODES + 127) / 128, 256, 0, stream>>>(
        xbuf, xbuf, N_NODES, W1, hbuf, N_NODES);
    agg_kernel<128><<<AGGB, 256, 0, stream>>>(hbuf, dis, off, csr, wgt, b1, xbuf, N_NODES);
    stats1_kernel<<<STATS_NB, 128, 0, stream>>>(xbuf, part);
    stats2_kernel<<<1, 128, 0, stream>>>(part, STATS_NB, g1, be1, bn_a, bn_b);
    bn_relu_l2_kernel<<<AGGB, 256, 0, stream>>>(xbuf, bn_a, bn_b, xbuf, N_NODES);

    // layer 2: (150000x128) @ (128x64)
    gemm_kernel<128, 64, 256><<<(N_NODES + 255) / 256, 256, 0, stream>>>(
        xbuf, xbuf, N_NODES, W2, hbuf, N_NODES);
    agg_kernel<64><<<AGGB, 256, 0, stream>>>(hbuf, dis, off, csr, wgt, b2, X, N_NODES);

    // loss
    zero_float_kernel<<<1, 1, 0, stream>>>(out);
    loss_kernel<<<(BATCH + 3) / 4, 256, 0, stream>>>(X, user_id, pos_item, neg_item, out);
}

// Round 5
// 1443.488 us; speedup vs baseline: 1.8873x; 1.0958x over previous
//
#include <hip/hip_runtime.h>
#include <hip/hip_bf16.h>
#include <math.h>

#define USER_NUM 100000
#define ITEM_NUM 50000
#define N_NODES  150000
#define N_EDGES  2400000
#define OUT_DIM  64
#define HID_DIM  128
#define BATCH    4096
#define EPS_BN   1e-5f

typedef unsigned short ushort_t;
typedef unsigned int uint_t;

// fp32 -> bf16 (round-to-nearest-even), and back
__device__ __forceinline__ ushort_t f2bf(float f) {
    uint_t u = __float_as_uint(f);
    u += 0x7FFFu + ((u >> 16) & 1u);
    return (ushort_t)(u >> 16);
}
__device__ __forceinline__ float bf2f(ushort_t s) {
    return __uint_as_float((uint_t)s << 16);
}

// ---------------- preprocessing ----------------

__global__ __launch_bounds__(256) void zero_int_kernel(int* __restrict__ p, int n) {
    int i = blockIdx.x * 256 + threadIdx.x;
    if (i < n) p[i] = 0;
}

__global__ __launch_bounds__(256) void count_kernel(const int* __restrict__ dst, int* __restrict__ cnt) {
    int i = blockIdx.x * 256 + threadIdx.x;
    if (i < N_EDGES) atomicAdd(&cnt[dst[i]], 1);
}

__global__ __launch_bounds__(256) void dis_kernel(const int* __restrict__ cnt, float* __restrict__ dis) {
    int i = blockIdx.x * 256 + threadIdx.x;
    if (i < N_NODES) dis[i] = rsqrtf(1.0f + (float)cnt[i]);
}

// 3-pass scan: per-block sums -> scan of block sums -> emit offsets
#define SC_ELEM 1024
#define SC_NB   ((N_NODES + SC_ELEM - 1) / SC_ELEM)   // 147

__global__ __launch_bounds__(256) void scan_part_kernel(const int* __restrict__ cnt,
                                                        int* __restrict__ psum) {
    __shared__ int red[4];
    int tid = threadIdx.x;
    int base = blockIdx.x * SC_ELEM + tid * 4;
    int s = 0;
#pragma unroll
    for (int j = 0; j < 4; j++) { int i = base + j; if (i < N_NODES) s += cnt[i]; }
#pragma unroll
    for (int d = 1; d < 64; d <<= 1) s += __shfl_xor(s, d);
    if ((tid & 63) == 0) red[tid >> 6] = s;
    __syncthreads();
    if (tid == 0) psum[blockIdx.x] = red[0] + red[1] + red[2] + red[3];
}

__global__ __launch_bounds__(256) void scan_mid_kernel(int* __restrict__ psum,
                                                       int* __restrict__ off, int nb) {
    __shared__ int lds[256];
    int tid = threadIdx.x;
    int v = (tid < nb) ? psum[tid] : 0;
    lds[tid] = v;
    __syncthreads();
    for (int d = 1; d < 256; d <<= 1) {
        int t = (tid >= d) ? lds[tid - d] : 0;
        __syncthreads();
        lds[tid] += t;
        __syncthreads();
    }
    if (tid < nb) psum[tid] = lds[tid] - v;   // exclusive
    if (tid == 0) off[N_NODES] = lds[255];
}

__global__ __launch_bounds__(256) void scan_emit_kernel(const int* __restrict__ cnt,
                                                        const int* __restrict__ psum,
                                                        int* __restrict__ off,
                                                        int* __restrict__ cur) {
    __shared__ int lds[256];
    int tid = threadIdx.x;
    int base = blockIdx.x * SC_ELEM + tid * 4;
    int v[4]; int s = 0;
#pragma unroll
    for (int j = 0; j < 4; j++) {
        int i = base + j;
        v[j] = (i < N_NODES) ? cnt[i] : 0;
        s += v[j];
    }
    lds[tid] = s;
    __syncthreads();
    for (int d = 1; d < 256; d <<= 1) {
        int t = (tid >= d) ? lds[tid - d] : 0;
        __syncthreads();
        lds[tid] += t;
        __syncthreads();
    }
    int run = psum[blockIdx.x] + lds[tid] - s;
#pragma unroll
    for (int j = 0; j < 4; j++) {
        int i = base + j;
        if (i < N_NODES) { off[i] = run; cur[i] = run; }
        run += v[j];
    }
}

__global__ __launch_bounds__(256) void fill_kernel(const int* __restrict__ src, const int* __restrict__ dst,
                                                   const float* __restrict__ dis,
                                                   int* __restrict__ cursor,
                                                   int* __restrict__ csr_src,
                                                   float* __restrict__ wgt) {
    int i = blockIdx.x * 256 + threadIdx.x;
    if (i < N_EDGES) {
        int s = src[i];
        int d = dst[i];
        int p = atomicAdd(&cursor[d], 1);
        csr_src[p] = s;
        wgt[p] = dis[s] * dis[d];
    }
}

// ---------------- GEMM: out[M][DOUT] = x[M][DIN] @ W[DIN][DOUT], bf16 output ----------------
// 256 threads, block tile MBLK x DOUT, micro-tile 8x8 per thread,
// K-chunks of 32 staged in LDS with reg-staged prefetch of next chunk.

template<int DIN, int DOUT, int MBLK>
__global__ __launch_bounds__(256) void gemm_kernel(const float* __restrict__ xlo,
                                                   const float* __restrict__ xhi, int split,
                                                   const float* __restrict__ W,
                                                   ushort_t* __restrict__ out, int nrows) {
    constexpr int KC    = 32;
    constexpr int NC    = DIN / KC;
    constexpr int XS_PT = MBLK / 32;      // float4 x-loads per thread per chunk
    constexpr int WS_PT = DOUT / 32;      // float4 w-loads per thread per chunk
    constexpr int NCOLG = DOUT / 8;

    __shared__ float xs[MBLK][KC + 1];    // +1 pad: conflict-free column reads
    __shared__ float ws[KC][DOUT];

    const int tid  = threadIdx.x;
    const int row0 = blockIdx.x * MBLK;
    const int colg = tid % NCOLG;
    const int rowg = tid / NCOLG;

    float4 xr[XS_PT], wr[WS_PT];

    auto load_chunk = [&](int kc) {
#pragma unroll
        for (int i = 0; i < XS_PT; i++) {
            int idx = i * 256 + tid;
            int m = idx >> 3, kq = idx & 7;
            int row = row0 + m; if (row > nrows - 1) row = nrows - 1;
            const float* rp = (row < split) ? xlo + (size_t)row * DIN
                                            : xhi + (size_t)(row - split) * DIN;
            xr[i] = *(const float4*)(rp + kc + kq * 4);
        }
#pragma unroll
        for (int i = 0; i < WS_PT; i++) {
            int idx = i * 256 + tid;
            int n4 = idx % (DOUT / 4), kk = idx / (DOUT / 4);
            wr[i] = *(const float4*)(W + (size_t)(kc + kk) * DOUT + n4 * 4);
        }
    };
    auto write_chunk = [&]() {
#pragma unroll
        for (int i = 0; i < XS_PT; i++) {
            int idx = i * 256 + tid;
            int m = idx >> 3, kq = idx & 7;
            xs[m][kq * 4 + 0] = xr[i].x;
            xs[m][kq * 4 + 1] = xr[i].y;
            xs[m][kq * 4 + 2] = xr[i].z;
            xs[m][kq * 4 + 3] = xr[i].w;
        }
#pragma unroll
        for (int i = 0; i < WS_PT; i++) {
            int idx = i * 256 + tid;
            int n4 = idx % (DOUT / 4), kk = idx / (DOUT / 4);
            *(float4*)&ws[kk][n4 * 4] = wr[i];
        }
    };

    float acc[8][8];
#pragma unroll
    for (int r = 0; r < 8; r++)
#pragma unroll
        for (int c = 0; c < 8; c++) acc[r][c] = 0.f;

    load_chunk(0);
    write_chunk();
    __syncthreads();

    for (int c = 0; c < NC; c++) {
        if (c + 1 < NC) load_chunk((c + 1) * KC);   // prefetch under compute
#pragma unroll 4
        for (int k = 0; k < KC; k++) {
            float4 wa = *(const float4*)&ws[k][colg * 8];
            float4 wb = *(const float4*)&ws[k][colg * 8 + 4];
            float xv[8];
#pragma unroll
            for (int r = 0; r < 8; r++) xv[r] = xs[rowg * 8 + r][k];
#pragma unroll
            for (int r = 0; r < 8; r++) {
                acc[r][0] = fmaf(xv[r], wa.x, acc[r][0]);
                acc[r][1] = fmaf(xv[r], wa.y, acc[r][1]);
                acc[r][2] = fmaf(xv[r], wa.z, acc[r][2]);
                acc[r][3] = fmaf(xv[r], wa.w, acc[r][3]);
                acc[r][4] = fmaf(xv[r], wb.x, acc[r][4]);
                acc[r][5] = fmaf(xv[r], wb.y, acc[r][5]);
                acc[r][6] = fmaf(xv[r], wb.z, acc[r][6]);
                acc[r][7] = fmaf(xv[r], wb.w, acc[r][7]);
            }
        }
        __syncthreads();
        if (c + 1 < NC) { write_chunk(); __syncthreads(); }
    }

#pragma unroll
    for (int r = 0; r < 8; r++) {
        int row = row0 + rowg * 8 + r;
        if (row < nrows) {
            uint4 pk;
            pk.x = (uint_t)f2bf(acc[r][0]) | ((uint_t)f2bf(acc[r][1]) << 16);
            pk.y = (uint_t)f2bf(acc[r][2]) | ((uint_t)f2bf(acc[r][3]) << 16);
            pk.z = (uint_t)f2bf(acc[r][4]) | ((uint_t)f2bf(acc[r][5]) << 16);
            pk.w = (uint_t)f2bf(acc[r][6]) | ((uint_t)f2bf(acc[r][7]) << 16);
            *(uint4*)&out[(size_t)row * DOUT + colg * 8] = pk;
        }
    }
}

// ---------------- edge aggregation (CSR gather over bf16 h, one wave per node) ----------------
// out[i] = sum_e wgt[e]*h[csr[e]] + h[i]*dis[i]^2 + bias   (fp32 accumulate/output)

template<int DOUT>
__global__ __launch_bounds__(256) void agg_kernel(const ushort_t* __restrict__ h,
                                                  const float* __restrict__ dis,
                                                  const int* __restrict__ off,
                                                  const int* __restrict__ csr,
                                                  const float* __restrict__ wgt,
                                                  const float* __restrict__ bias,
                                                  float* __restrict__ out, int n) {
    int wave = threadIdx.x >> 6;
    int lane = threadIdx.x & 63;
    int node = blockIdx.x * 4 + wave;
    if (node >= n) return;
    float di  = dis[node];
    int   beg = off[node], end = off[node + 1];
    if (DOUT == 128) {
        const uint_t* hp = (const uint_t*)h;   // 64 uints (128 bf16) per row
        float ax = 0.f, ay = 0.f;
        int e = beg;
        for (; e + 4 <= end; e += 4) {
            int s0 = csr[e], s1 = csr[e + 1], s2 = csr[e + 2], s3 = csr[e + 3];
            float w0 = wgt[e], w1 = wgt[e + 1], w2 = wgt[e + 2], w3 = wgt[e + 3];
            uint_t u0 = hp[(size_t)s0 * 64 + lane];
            uint_t u1 = hp[(size_t)s1 * 64 + lane];
            uint_t u2 = hp[(size_t)s2 * 64 + lane];
            uint_t u3 = hp[(size_t)s3 * 64 + lane];
            ax = fmaf(__uint_as_float(u0 << 16), w0, ax);
            ay = fmaf(__uint_as_float(u0 & 0xFFFF0000u), w0, ay);
            ax = fmaf(__uint_as_float(u1 << 16), w1, ax);
            ay = fmaf(__uint_as_float(u1 & 0xFFFF0000u), w1, ay);
            ax = fmaf(__uint_as_float(u2 << 16), w2, ax);
            ay = fmaf(__uint_as_float(u2 & 0xFFFF0000u), w2, ay);
            ax = fmaf(__uint_as_float(u3 << 16), w3, ax);
            ay = fmaf(__uint_as_float(u3 & 0xFFFF0000u), w3, ay);
        }
        for (; e < end; e++) {
            int s = csr[e]; float wv = wgt[e];
            uint_t u = hp[(size_t)s * 64 + lane];
            ax = fmaf(__uint_as_float(u << 16), wv, ax);
            ay = fmaf(__uint_as_float(u & 0xFFFF0000u), wv, ay);
        }
        uint_t us = hp[(size_t)node * 64 + lane];
        float2 bb = ((const float2*)bias)[lane];
        float dd = di * di;
        float2 o;
        o.x = ax + __uint_as_float(us << 16) * dd + bb.x;
        o.y = ay + __uint_as_float(us & 0xFFFF0000u) * dd + bb.y;
        ((float2*)out)[(size_t)node * 64 + lane] = o;
    } else {
        float ax = 0.f;
        int e = beg;
        for (; e + 4 <= end; e += 4) {
            int s0 = csr[e], s1 = csr[e + 1], s2 = csr[e + 2], s3 = csr[e + 3];
            float w0 = wgt[e], w1 = wgt[e + 1], w2 = wgt[e + 2], w3 = wgt[e + 3];
            float h0 = bf2f(h[(size_t)s0 * 64 + lane]);
            float h1 = bf2f(h[(size_t)s1 * 64 + lane]);
            float h2 = bf2f(h[(size_t)s2 * 64 + lane]);
            float h3 = bf2f(h[(size_t)s3 * 64 + lane]);
            ax = fmaf(h0, w0, ax); ax = fmaf(h1, w1, ax);
            ax = fmaf(h2, w2, ax); ax = fmaf(h3, w3, ax);
        }
        for (; e < end; e++) ax = fmaf(bf2f(h[(size_t)csr[e] * 64 + lane]), wgt[e], ax);
        float hs = bf2f(h[(size_t)node * 64 + lane]);
        out[(size_t)node * 64 + lane] = ax + hs * di * di + bias[lane];
    }
}

// ---------------- BN stats (two-stage, double partials) ----------------

#define STATS_NB 512

__global__ __launch_bounds__(128) void stats1_kernel(const float* __restrict__ x,
                                                     double* __restrict__ part) {
    int col = threadIdx.x;
    double a = 0.0, b = 0.0;
    for (int row = blockIdx.x; row < N_NODES; row += STATS_NB) {
        float v = x[(size_t)row * HID_DIM + col];
        a += v;
        b += (double)v * (double)v;
    }
    part[(size_t)blockIdx.x * 256 + col]       = a;
    part[(size_t)blockIdx.x * 256 + 128 + col] = b;
}

__global__ __launch_bounds__(128) void stats2_kernel(const double* __restrict__ part, int npart,
                                                     const float* __restrict__ g,
                                                     const float* __restrict__ beta,
                                                     float* __restrict__ a_out,
                                                     float* __restrict__ b_out) {
    int col = threadIdx.x;
    double s1 = 0.0, s2 = 0.0;
    for (int p = 0; p < npart; p++) {
        s1 += part[(size_t)p * 256 + col];
        s2 += part[(size_t)p * 256 + 128 + col];
    }
    double mean = s1 / (double)N_NODES;
    double var  = s2 / (double)N_NODES - mean * mean;
    float inv = rsqrtf((float)var + EPS_BN);
    float aa  = g[col] * inv;
    a_out[col] = aa;
    b_out[col] = beta[col] - (float)mean * aa;
}

// ---------------- fused BN-apply + ReLU + row L2-norm (wave per row) ----------------

__global__ __launch_bounds__(256) void bn_relu_l2_kernel(const float* __restrict__ in,
                                                         const float* __restrict__ a,
                                                         const float* __restrict__ b,
                                                         float* __restrict__ outp, int n) {
    int wave = threadIdx.x >> 6;
    int lane = threadIdx.x & 63;
    int row  = blockIdx.x * 4 + wave;
    if (row >= n) return;
    float2 v  = *(const float2*)(in + (size_t)row * 128 + lane * 2);
    float2 aa = *(const float2*)(a + lane * 2);
    float2 bb = *(const float2*)(b + lane * 2);
    float y0 = fmaxf(fmaf(v.x, aa.x, bb.x), 0.f);
    float y1 = fmaxf(fmaf(v.y, aa.y, bb.y), 0.f);
    float ss = y0 * y0 + y1 * y1;
#pragma unroll
    for (int d = 32; d >= 1; d >>= 1) ss += __shfl_xor(ss, d);
    float nn  = sqrtf(ss);
    float inv = 1.f / fmaxf(nn, 1e-12f);
    outp[(size_t)row * 128 + lane * 2 + 0] = y0 * inv;
    outp[(size_t)row * 128 + lane * 2 + 1] = y1 * inv;
}

// ---------------- loss ----------------

__global__ void zero_float_kernel(float* p) { *p = 0.f; }

__global__ __launch_bounds__(256) void loss_kernel(const float* __restrict__ X,
                                                   const int* __restrict__ uid,
                                                   const int* __restrict__ pid,
                                                   const int* __restrict__ nid,
                                                   float* __restrict__ out0) {
    int wave = threadIdx.x >> 6;
    int lane = threadIdx.x & 63;
    int b = blockIdx.x * 4 + wave;
    if (b >= BATCH) return;
    const float* u = X + (size_t)uid[b] * OUT_DIM;
    const float* p = X + (size_t)(USER_NUM + pid[b]) * OUT_DIM;
    const float* q = X + (size_t)(USER_NUM + nid[b]) * OUT_DIM;
    float uv = u[lane];
    float ps = uv * p[lane];
    float ns = uv * q[lane];
#pragma unroll
    for (int d = 32; d >= 1; d >>= 1) {
        ps += __shfl_xor(ps, d);
        ns += __shfl_xor(ns, d);
    }
    if (lane == 0) {
        float t  = ns - ps;                                   // -(pos - neg)
        float sp = fmaxf(t, 0.f) + log1pf(expf(-fabsf(t)));   // softplus(t)
        atomicAdd(out0, sp * (1.0f / BATCH));
    }
}

// ---------------- launch ----------------

extern "C" void kernel_launch(void* const* d_in, const int* in_sizes, int n_in,
                              void* d_out, int out_size, void* d_ws, size_t ws_size,
                              hipStream_t stream) {
    const float* user_emb = (const float*)d_in[0];
    const float* item_emb = (const float*)d_in[1];
    const float* W0  = (const float*)d_in[2];
    const float* b0  = (const float*)d_in[3];
    const float* g0  = (const float*)d_in[4];
    const float* be0 = (const float*)d_in[5];
    const float* W1  = (const float*)d_in[6];
    const float* b1  = (const float*)d_in[7];
    const float* g1  = (const float*)d_in[8];
    const float* be1 = (const float*)d_in[9];
    const float* W2  = (const float*)d_in[10];
    const float* b2  = (const float*)d_in[11];
    const int* user_id  = (const int*)d_in[12];
    const int* pos_item = (const int*)d_in[13];
    const int* neg_item = (const int*)d_in[14];
    const int* edge     = (const int*)d_in[15];
    const int* src = edge;
    const int* dst = edge + N_EDGES;

    char* w = (char*)d_ws;
    auto alloc = [&](size_t bytes) -> char* {
        char* r = w;
        w += (bytes + 255) / 256 * 256;
        return r;
    };
    int*      cnt  = (int*)alloc((size_t)N_NODES * 4);
    int*      off  = (int*)alloc((size_t)(N_NODES + 1) * 4);
    int*      cur  = (int*)alloc((size_t)N_NODES * 4);
    int*      csr  = (int*)alloc((size_t)N_EDGES * 4);
    float*    wgt  = (float*)alloc((size_t)N_EDGES * 4);
    float*    dis  = (float*)alloc((size_t)N_NODES * 4);
    int*      psum = (int*)alloc((size_t)SC_NB * 4);
    double*   part = (double*)alloc((size_t)STATS_NB * 256 * 8);
    float*    bn_a = (float*)alloc(128 * 4);
    float*    bn_b = (float*)alloc(128 * 4);
    ushort_t* hbuf = (ushort_t*)alloc((size_t)N_NODES * HID_DIM * 2);   // bf16 GEMM output
    float*    xbuf = (float*)alloc((size_t)N_NODES * HID_DIM * 4);

    float* out = (float*)d_out;
    float* X   = out + 1;   // node embeddings region (150000 x 64)

    const int EB = (N_EDGES + 255) / 256;
    const int NB = (N_NODES + 255) / 256;
    const int AGGB = (N_NODES + 3) / 4;

    // preprocessing: degree, dis, CSR (+ per-edge weights)
    zero_int_kernel<<<NB, 256, 0, stream>>>(cnt, N_NODES);
    count_kernel<<<EB, 256, 0, stream>>>(dst, cnt);
    dis_kernel<<<NB, 256, 0, stream>>>(cnt, dis);
    scan_part_kernel<<<SC_NB, 256, 0, stream>>>(cnt, psum);
    scan_mid_kernel<<<1, 256, 0, stream>>>(psum, off, SC_NB);
    scan_emit_kernel<<<SC_NB, 256, 0, stream>>>(cnt, psum, off, cur);
    fill_kernel<<<EB, 256, 0, stream>>>(src, dst, dis, cur, csr, wgt);

    // layer 0: (150000x64) @ (64x128)
    gemm_kernel<64, 128, 128><<<(N_NODES + 127) / 128, 256, 0, stream>>>(
        user_emb, item_emb, USER_NUM, W0, hbuf, N_NODES);
    agg_kernel<128><<<AGGB, 256, 0, stream>>>(hbuf, dis, off, csr, wgt, b0, xbuf, N_NODES);
    stats1_kernel<<<STATS_NB, 128, 0, stream>>>(xbuf, part);
    stats2_kernel<<<1, 128, 0, stream>>>(part, STATS_NB, g0, be0, bn_a, bn_b);
    bn_relu_l2_kernel<<<AGGB, 256, 0, stream>>>(xbuf, bn_a, bn_b, xbuf, N_NODES);

    // layer 1: (150000x128) @ (128x128)
    gemm_kernel<128, 128, 128><<<(N_NODES + 127) / 128, 256, 0, stream>>>(
        xbuf, xbuf, N_NODES, W1, hbuf, N_NODES);
    agg_kernel<128><<<AGGB, 256, 0, stream>>>(hbuf, dis, off, csr, wgt, b1, xbuf, N_NODES);
    stats1_kernel<<<STATS_NB, 128, 0, stream>>>(xbuf, part);
    stats2_kernel<<<1, 128, 0, stream>>>(part, STATS_NB, g1, be1, bn_a, bn_b);
    bn_relu_l2_kernel<<<AGGB, 256, 0, stream>>>(xbuf, bn_a, bn_b, xbuf, N_NODES);

    // layer 2: (150000x128) @ (128x64)
    gemm_kernel<128, 64, 256><<<(N_NODES + 255) / 256, 256, 0, stream>>>(
        xbuf, xbuf, N_NODES, W2, hbuf, N_NODES);
    agg_kernel<64><<<AGGB, 256, 0, stream>>>(hbuf, dis, off, csr, wgt, b2, X, N_NODES);

    // loss
    zero_float_kernel<<<1, 1, 0, stream>>>(out);
    loss_kernel<<<(BATCH + 3) / 4, 256, 0, stream>>>(X, user_id, pos_item, neg_item, out);
}

// Round 7
// 1388.870 us; speedup vs baseline: 1.9615x; 1.0393x over previous
//
#include <hip/hip_runtime.h>
#include <hip/hip_bf16.h>
#include <math.h>

#define USER_NUM 100000
#define ITEM_NUM 50000
#define N_NODES  150000
#define N_EDGES  2400000
#define OUT_DIM  64
#define HID_DIM  128
#define BATCH    4096
#define EPS_BN   1e-5f

typedef unsigned short ushort_t;
typedef unsigned int uint_t;

// fp32 -> bf16 (round-to-nearest-even), and back
__device__ __forceinline__ ushort_t f2bf(float f) {
    uint_t u = __float_as_uint(f);
    u += 0x7FFFu + ((u >> 16) & 1u);
    return (ushort_t)(u >> 16);
}
__device__ __forceinline__ float bf2f(ushort_t s) {
    return __uint_as_float((uint_t)s << 16);
}

// ---------------- preprocessing ----------------

__global__ __launch_bounds__(256) void zero_int_kernel(int* __restrict__ p, int n) {
    int i = blockIdx.x * 256 + threadIdx.x;
    if (i < n) p[i] = 0;
}

__global__ __launch_bounds__(256) void count_kernel(const int* __restrict__ dst, int* __restrict__ cnt) {
    int i = blockIdx.x * 256 + threadIdx.x;
    if (i < N_EDGES) atomicAdd(&cnt[dst[i]], 1);
}

__global__ __launch_bounds__(256) void dis_kernel(const int* __restrict__ cnt, float* __restrict__ dis) {
    int i = blockIdx.x * 256 + threadIdx.x;
    if (i < N_NODES) dis[i] = rsqrtf(1.0f + (float)cnt[i]);
}

// 3-pass scan: per-block sums -> scan of block sums -> emit offsets
#define SC_ELEM 1024
#define SC_NB   ((N_NODES + SC_ELEM - 1) / SC_ELEM)   // 147

__global__ __launch_bounds__(256) void scan_part_kernel(const int* __restrict__ cnt,
                                                        int* __restrict__ psum) {
    __shared__ int red[4];
    int tid = threadIdx.x;
    int base = blockIdx.x * SC_ELEM + tid * 4;
    int s = 0;
#pragma unroll
    for (int j = 0; j < 4; j++) { int i = base + j; if (i < N_NODES) s += cnt[i]; }
#pragma unroll
    for (int d = 1; d < 64; d <<= 1) s += __shfl_xor(s, d);
    if ((tid & 63) == 0) red[tid >> 6] = s;
    __syncthreads();
    if (tid == 0) psum[blockIdx.x] = red[0] + red[1] + red[2] + red[3];
}

__global__ __launch_bounds__(256) void scan_mid_kernel(int* __restrict__ psum,
                                                       int* __restrict__ off, int nb) {
    __shared__ int lds[256];
    int tid = threadIdx.x;
    int v = (tid < nb) ? psum[tid] : 0;
    lds[tid] = v;
    __syncthreads();
    for (int d = 1; d < 256; d <<= 1) {
        int t = (tid >= d) ? lds[tid - d] : 0;
        __syncthreads();
        lds[tid] += t;
        __syncthreads();
    }
    if (tid < nb) psum[tid] = lds[tid] - v;   // exclusive
    if (tid == 0) off[N_NODES] = lds[255];
}

__global__ __launch_bounds__(256) void scan_emit_kernel(const int* __restrict__ cnt,
                                                        const int* __restrict__ psum,
                                                        int* __restrict__ off,
                                                        int* __restrict__ cur) {
    __shared__ int lds[256];
    int tid = threadIdx.x;
    int base = blockIdx.x * SC_ELEM + tid * 4;
    int v[4]; int s = 0;
#pragma unroll
    for (int j = 0; j < 4; j++) {
        int i = base + j;
        v[j] = (i < N_NODES) ? cnt[i] : 0;
        s += v[j];
    }
    lds[tid] = s;
    __syncthreads();
    for (int d = 1; d < 256; d <<= 1) {
        int t = (tid >= d) ? lds[tid - d] : 0;
        __syncthreads();
        lds[tid] += t;
        __syncthreads();
    }
    int run = psum[blockIdx.x] + lds[tid] - s;
#pragma unroll
    for (int j = 0; j < 4; j++) {
        int i = base + j;
        if (i < N_NODES) { off[i] = run; cur[i] = run; }
        run += v[j];
    }
}

// CSR entry: .x = src node, .y = bit-pattern of edge weight dis[src]*dis[dst]
__global__ __launch_bounds__(256) void fill_kernel(const int* __restrict__ src, const int* __restrict__ dst,
                                                   const float* __restrict__ dis,
                                                   int* __restrict__ cursor,
                                                   uint2* __restrict__ csr8) {
    int i = blockIdx.x * 256 + threadIdx.x;
    if (i < N_EDGES) {
        int s = src[i];
        int d = dst[i];
        int p = atomicAdd(&cursor[d], 1);
        uint2 e;
        e.x = (uint_t)s;
        e.y = __float_as_uint(dis[s] * dis[d]);
        csr8[p] = e;
    }
}

// ---------------- GEMM: out[M][DOUT] = x[M][DIN] @ W[DIN][DOUT], bf16 output ----------------
// XT = float or ushort_t (bf16) input. 256 threads, block tile MBLK x DOUT,
// micro-tile 8x8 per thread, K-chunks of 32 in LDS with reg-staged prefetch.

__device__ __forceinline__ float4 load4(const float* p) { return *(const float4*)p; }
__device__ __forceinline__ float4 load4(const ushort_t* p) {
    ushort4 u = *(const ushort4*)p;
    return make_float4(bf2f(u.x), bf2f(u.y), bf2f(u.z), bf2f(u.w));
}

template<typename XT, int DIN, int DOUT, int MBLK>
__global__ __launch_bounds__(256) void gemm_kernel(const XT* __restrict__ xlo,
                                                   const XT* __restrict__ xhi, int split,
                                                   const float* __restrict__ W,
                                                   ushort_t* __restrict__ out, int nrows) {
    constexpr int KC    = 32;
    constexpr int NC    = DIN / KC;
    constexpr int XS_PT = MBLK / 32;      // 4-elem x-loads per thread per chunk
    constexpr int WS_PT = DOUT / 32;      // float4 w-loads per thread per chunk
    constexpr int NCOLG = DOUT / 8;

    __shared__ float xs[MBLK][KC + 1];    // +1 pad: conflict-free column reads
    __shared__ float ws[KC][DOUT];

    const int tid  = threadIdx.x;
    const int row0 = blockIdx.x * MBLK;
    const int colg = tid % NCOLG;
    const int rowg = tid / NCOLG;

    float4 xr[XS_PT], wr[WS_PT];

    auto load_chunk = [&](int kc) {
#pragma unroll
        for (int i = 0; i < XS_PT; i++) {
            int idx = i * 256 + tid;
            int m = idx >> 3, kq = idx & 7;
            int row = row0 + m; if (row > nrows - 1) row = nrows - 1;
            const XT* rp = (row < split) ? xlo + (size_t)row * DIN
                                         : xhi + (size_t)(row - split) * DIN;
            xr[i] = load4(rp + kc + kq * 4);
        }
#pragma unroll
        for (int i = 0; i < WS_PT; i++) {
            int idx = i * 256 + tid;
            int n4 = idx % (DOUT / 4), kk = idx / (DOUT / 4);
            wr[i] = *(const float4*)(W + (size_t)(kc + kk) * DOUT + n4 * 4);
        }
    };
    auto write_chunk = [&]() {
#pragma unroll
        for (int i = 0; i < XS_PT; i++) {
            int idx = i * 256 + tid;
            int m = idx >> 3, kq = idx & 7;
            xs[m][kq * 4 + 0] = xr[i].x;
            xs[m][kq * 4 + 1] = xr[i].y;
            xs[m][kq * 4 + 2] = xr[i].z;
            xs[m][kq * 4 + 3] = xr[i].w;
        }
#pragma unroll
        for (int i = 0; i < WS_PT; i++) {
            int idx = i * 256 + tid;
            int n4 = idx % (DOUT / 4), kk = idx / (DOUT / 4);
            *(float4*)&ws[kk][n4 * 4] = wr[i];
        }
    };

    float acc[8][8];
#pragma unroll
    for (int r = 0; r < 8; r++)
#pragma unroll
        for (int c = 0; c < 8; c++) acc[r][c] = 0.f;

    load_chunk(0);
    write_chunk();
    __syncthreads();

    for (int c = 0; c < NC; c++) {
        if (c + 1 < NC) load_chunk((c + 1) * KC);   // prefetch under compute
#pragma unroll 4
        for (int k = 0; k < KC; k++) {
            float4 wa = *(const float4*)&ws[k][colg * 8];
            float4 wb = *(const float4*)&ws[k][colg * 8 + 4];
            float xv[8];
#pragma unroll
            for (int r = 0; r < 8; r++) xv[r] = xs[rowg * 8 + r][k];
#pragma unroll
            for (int r = 0; r < 8; r++) {
                acc[r][0] = fmaf(xv[r], wa.x, acc[r][0]);
                acc[r][1] = fmaf(xv[r], wa.y, acc[r][1]);
                acc[r][2] = fmaf(xv[r], wa.z, acc[r][2]);
                acc[r][3] = fmaf(xv[r], wa.w, acc[r][3]);
                acc[r][4] = fmaf(xv[r], wb.x, acc[r][4]);
                acc[r][5] = fmaf(xv[r], wb.y, acc[r][5]);
                acc[r][6] = fmaf(xv[r], wb.z, acc[r][6]);
                acc[r][7] = fmaf(xv[r], wb.w, acc[r][7]);
            }
        }
        __syncthreads();
        if (c + 1 < NC) { write_chunk(); __syncthreads(); }
    }

#pragma unroll
    for (int r = 0; r < 8; r++) {
        int row = row0 + rowg * 8 + r;
        if (row < nrows) {
            uint4 pk;
            pk.x = (uint_t)f2bf(acc[r][0]) | ((uint_t)f2bf(acc[r][1]) << 16);
            pk.y = (uint_t)f2bf(acc[r][2]) | ((uint_t)f2bf(acc[r][3]) << 16);
            pk.z = (uint_t)f2bf(acc[r][4]) | ((uint_t)f2bf(acc[r][5]) << 16);
            pk.w = (uint_t)f2bf(acc[r][6]) | ((uint_t)f2bf(acc[r][7]) << 16);
            *(uint4*)&out[(size_t)row * DOUT + colg * 8] = pk;
        }
    }
}

// ---------------- edge aggregation (CSR gather over bf16 h, one wave per node) ----------------
// out[i] = sum_e w_e*h[s_e] + h[i]*dis[i]^2 + bias   (fp32 accumulate/output)

template<int DOUT>
__global__ __launch_bounds__(256) void agg_kernel(const ushort_t* __restrict__ h,
                                                  const float* __restrict__ dis,
                                                  const int* __restrict__ off,
                                                  const uint2* __restrict__ csr8,
                                                  const float* __restrict__ bias,
                                                  float* __restrict__ out, int n) {
    int wave = threadIdx.x >> 6;
    int lane = threadIdx.x & 63;
    int node = blockIdx.x * 4 + wave;
    if (node >= n) return;
    float di  = dis[node];
    int   beg = off[node], end = off[node + 1];
    if (DOUT == 128) {
        const uint_t* hp = (const uint_t*)h;   // 64 uints (128 bf16) per row
        float ax = 0.f, ay = 0.f;
        int e = beg;
        for (; e + 4 <= end; e += 4) {
            uint2 e0 = csr8[e], e1 = csr8[e + 1], e2 = csr8[e + 2], e3 = csr8[e + 3];
            uint_t u0 = hp[(size_t)e0.x * 64 + lane];
            uint_t u1 = hp[(size_t)e1.x * 64 + lane];
            uint_t u2 = hp[(size_t)e2.x * 64 + lane];
            uint_t u3 = hp[(size_t)e3.x * 64 + lane];
            float w0 = __uint_as_float(e0.y), w1 = __uint_as_float(e1.y);
            float w2 = __uint_as_float(e2.y), w3 = __uint_as_float(e3.y);
            ax = fmaf(__uint_as_float(u0 << 16), w0, ax);
            ay = fmaf(__uint_as_float(u0 & 0xFFFF0000u), w0, ay);
            ax = fmaf(__uint_as_float(u1 << 16), w1, ax);
            ay = fmaf(__uint_as_float(u1 & 0xFFFF0000u), w1, ay);
            ax = fmaf(__uint_as_float(u2 << 16), w2, ax);
            ay = fmaf(__uint_as_float(u2 & 0xFFFF0000u), w2, ay);
            ax = fmaf(__uint_as_float(u3 << 16), w3, ax);
            ay = fmaf(__uint_as_float(u3 & 0xFFFF0000u), w3, ay);
        }
        for (; e < end; e++) {
            uint2 ev = csr8[e];
            float wv = __uint_as_float(ev.y);
            uint_t u = hp[(size_t)ev.x * 64 + lane];
            ax = fmaf(__uint_as_float(u << 16), wv, ax);
            ay = fmaf(__uint_as_float(u & 0xFFFF0000u), wv, ay);
        }
        uint_t us = hp[(size_t)node * 64 + lane];
        float2 bb = ((const float2*)bias)[lane];
        float dd = di * di;
        float2 o;
        o.x = ax + __uint_as_float(us << 16) * dd + bb.x;
        o.y = ay + __uint_as_float(us & 0xFFFF0000u) * dd + bb.y;
        ((float2*)out)[(size_t)node * 64 + lane] = o;
    } else {
        float ax = 0.f;
        int e = beg;
        for (; e + 4 <= end; e += 4) {
            uint2 e0 = csr8[e], e1 = csr8[e + 1], e2 = csr8[e + 2], e3 = csr8[e + 3];
            float h0 = bf2f(h[(size_t)e0.x * 64 + lane]);
            float h1 = bf2f(h[(size_t)e1.x * 64 + lane]);
            float h2 = bf2f(h[(size_t)e2.x * 64 + lane]);
            float h3 = bf2f(h[(size_t)e3.x * 64 + lane]);
            ax = fmaf(h0, __uint_as_float(e0.y), ax);
            ax = fmaf(h1, __uint_as_float(e1.y), ax);
            ax = fmaf(h2, __uint_as_float(e2.y), ax);
            ax = fmaf(h3, __uint_as_float(e3.y), ax);
        }
        for (; e < end; e++) {
            uint2 ev = csr8[e];
            ax = fmaf(bf2f(h[(size_t)ev.x * 64 + lane]), __uint_as_float(ev.y), ax);
        }
        float hs = bf2f(h[(size_t)node * 64 + lane]);
        out[(size_t)node * 64 + lane] = ax + hs * di * di + bias[lane];
    }
}

// ---------------- BN stats (two-stage, double partials) ----------------

#define STATS_NB 512

__global__ __launch_bounds__(128) void stats1_kernel(const float* __restrict__ x,
                                                     double* __restrict__ part) {
    int col = threadIdx.x;
    double a = 0.0, b = 0.0;
    for (int row = blockIdx.x; row < N_NODES; row += STATS_NB) {
        float v = x[(size_t)row * HID_DIM + col];
        a += v;
        b += (double)v * (double)v;
    }
    part[(size_t)blockIdx.x * 256 + col]       = a;
    part[(size_t)blockIdx.x * 256 + 128 + col] = b;
}

__global__ __launch_bounds__(128) void stats2_kernel(const double* __restrict__ part, int npart,
                                                     const float* __restrict__ g,
                                                     const float* __restrict__ beta,
                                                     float* __restrict__ a_out,
                                                     float* __restrict__ b_out) {
    int col = threadIdx.x;
    double s1 = 0.0, s2 = 0.0;
    for (int p = 0; p < npart; p++) {
        s1 += part[(size_t)p * 256 + col];
        s2 += part[(size_t)p * 256 + 128 + col];
    }
    double mean = s1 / (double)N_NODES;
    double var  = s2 / (double)N_NODES - mean * mean;
    float inv = rsqrtf((float)var + EPS_BN);
    float aa  = g[col] * inv;
    a_out[col] = aa;
    b_out[col] = beta[col] - (float)mean * aa;
}

// ---------------- fused BN-apply + ReLU + row L2-norm -> bf16 (wave per row) ----------------

__global__ __launch_bounds__(256) void bn_relu_l2_kernel(const float* __restrict__ in,
                                                         const float* __restrict__ a,
                                                         const float* __restrict__ b,
                                                         uint_t* __restrict__ outp, int n) {
    int wave = threadIdx.x >> 6;
    int lane = threadIdx.x & 63;
    int row  = blockIdx.x * 4 + wave;
    if (row >= n) return;
    float2 v  = *(const float2*)(in + (size_t)row * 128 + lane * 2);
    float2 aa = *(const float2*)(a + lane * 2);
    float2 bb = *(const float2*)(b + lane * 2);
    float y0 = fmaxf(fmaf(v.x, aa.x, bb.x), 0.f);
    float y1 = fmaxf(fmaf(v.y, aa.y, bb.y), 0.f);
    float ss = y0 * y0 + y1 * y1;
#pragma unroll
    for (int d = 32; d >= 1; d >>= 1) ss += __shfl_xor(ss, d);
    float nn  = sqrtf(ss);
    float inv = 1.f / fmaxf(nn, 1e-12f);
    uint_t pk = (uint_t)f2bf(y0 * inv) | ((uint_t)f2bf(y1 * inv) << 16);
    outp[(size_t)row * 64 + lane] = pk;
}

// ---------------- loss ----------------

__global__ void zero_float_kernel(float* p) { *p = 0.f; }

__global__ __launch_bounds__(256) void loss_kernel(const float* __restrict__ X,
                                                   const int* __restrict__ uid,
                                                   const int* __restrict__ pid,
                                                   const int* __restrict__ nid,
                                                   float* __restrict__ out0) {
    int wave = threadIdx.x >> 6;
    int lane = threadIdx.x & 63;
    int b = blockIdx.x * 4 + wave;
    if (b >= BATCH) return;
    const float* u = X + (size_t)uid[b] * OUT_DIM;
    const float* p = X + (size_t)(USER_NUM + pid[b]) * OUT_DIM;
    const float* q = X + (size_t)(USER_NUM + nid[b]) * OUT_DIM;
    float uv = u[lane];
    float ps = uv * p[lane];
    float ns = uv * q[lane];
#pragma unroll
    for (int d = 32; d >= 1; d >>= 1) {
        ps += __shfl_xor(ps, d);
        ns += __shfl_xor(ns, d);
    }
    if (lane == 0) {
        float t  = ns - ps;                                   // -(pos - neg)
        float sp = fmaxf(t, 0.f) + log1pf(expf(-fabsf(t)));   // softplus(t)
        atomicAdd(out0, sp * (1.0f / BATCH));
    }
}

// ---------------- launch ----------------

extern "C" void kernel_launch(void* const* d_in, const int* in_sizes, int n_in,
                              void* d_out, int out_size, void* d_ws, size_t ws_size,
                              hipStream_t stream) {
    const float* user_emb = (const float*)d_in[0];
    const float* item_emb = (const float*)d_in[1];
    const float* W0  = (const float*)d_in[2];
    const float* b0  = (const float*)d_in[3];
    const float* g0  = (const float*)d_in[4];
    const float* be0 = (const float*)d_in[5];
    const float* W1  = (const float*)d_in[6];
    const float* b1  = (const float*)d_in[7];
    const float* g1  = (const float*)d_in[8];
    const float* be1 = (const float*)d_in[9];
    const float* W2  = (const float*)d_in[10];
    const float* b2  = (const float*)d_in[11];
    const int* user_id  = (const int*)d_in[12];
    const int* pos_item = (const int*)d_in[13];
    const int* neg_item = (const int*)d_in[14];
    const int* edge     = (const int*)d_in[15];
    const int* src = edge;
    const int* dst = edge + N_EDGES;

    char* w = (char*)d_ws;
    auto alloc = [&](size_t bytes) -> char* {
        char* r = w;
        w += (bytes + 255) / 256 * 256;
        return r;
    };
    int*      cnt  = (int*)alloc((size_t)N_NODES * 4);
    int*      off  = (int*)alloc((size_t)(N_NODES + 1) * 4);
    int*      cur  = (int*)alloc((size_t)N_NODES * 4);
    uint2*    csr8 = (uint2*)alloc((size_t)N_EDGES * 8);
    float*    dis  = (float*)alloc((size_t)N_NODES * 4);
    int*      psum = (int*)alloc((size_t)SC_NB * 4);
    double*   part = (double*)alloc((size_t)STATS_NB * 256 * 8);
    float*    bn_a = (float*)alloc(128 * 4);
    float*    bn_b = (float*)alloc(128 * 4);
    ushort_t* hbuf = (ushort_t*)alloc((size_t)N_NODES * HID_DIM * 2);   // bf16 GEMM output
    float*    xbuf = (float*)alloc((size_t)N_NODES * HID_DIM * 4);      // fp32 agg output
    ushort_t* xbf  = (ushort_t*)alloc((size_t)N_NODES * HID_DIM * 2);   // bf16 normalized x

    float* out = (float*)d_out;
    float* X   = out + 1;   // node embeddings region (150000 x 64)

    const int EB = (N_EDGES + 255) / 256;
    const int NB = (N_NODES + 255) / 256;
    const int AGGB = (N_NODES + 3) / 4;

    // preprocessing: degree, dis, CSR (+ fused per-edge weights)
    zero_int_kernel<<<NB, 256, 0, stream>>>(cnt, N_NODES);
    count_kernel<<<EB, 256, 0, stream>>>(dst, cnt);
    dis_kernel<<<NB, 256, 0, stream>>>(cnt, dis);
    scan_part_kernel<<<SC_NB, 256, 0, stream>>>(cnt, psum);
    scan_mid_kernel<<<1, 256, 0, stream>>>(psum, off, SC_NB);
    scan_emit_kernel<<<SC_NB, 256, 0, stream>>>(cnt, psum, off, cur);
    fill_kernel<<<EB, 256, 0, stream>>>(src, dst, dis, cur, csr8);

    // layer 0: (150000x64 fp32) @ (64x128)
    gemm_kernel<float, 64, 128, 128><<<(N_NODES + 127) / 128, 256, 0, stream>>>(
        user_emb, item_emb, USER_NUM, W0, hbuf, N_NODES);
    agg_kernel<128><<<AGGB, 256, 0, stream>>>(hbuf, dis, off, csr8, b0, xbuf, N_NODES);
    stats1_kernel<<<STATS_NB, 128, 0, stream>>>(xbuf, part);
    stats2_kernel<<<1, 128, 0, stream>>>(part, STATS_NB, g0, be0, bn_a, bn_b);
    bn_relu_l2_kernel<<<AGGB, 256, 0, stream>>>(xbuf, bn_a, bn_b, (uint_t*)xbf, N_NODES);

    // layer 1: (150000x128 bf16) @ (128x128)
    gemm_kernel<ushort_t, 128, 128, 128><<<(N_NODES + 127) / 128, 256, 0, stream>>>(
        xbf, xbf, N_NODES, W1, hbuf, N_NODES);
    agg_kernel<128><<<AGGB, 256, 0, stream>>>(hbuf, dis, off, csr8, b1, xbuf, N_NODES);
    stats1_kernel<<<STATS_NB, 128, 0, stream>>>(xbuf, part);
    stats2_kernel<<<1, 128, 0, stream>>>(part, STATS_NB, g1, be1, bn_a, bn_b);
    bn_relu_l2_kernel<<<AGGB, 256, 0, stream>>>(xbuf, bn_a, bn_b, (uint_t*)xbf, N_NODES);

    // layer 2: (150000x128 bf16) @ (128x64)
    gemm_kernel<ushort_t, 128, 64, 256><<<(N_NODES + 255) / 256, 256, 0, stream>>>(
        xbf, xbf, N_NODES, W2, hbuf, N_NODES);
    agg_kernel<64><<<AGGB, 256, 0, stream>>>(hbuf, dis, off, csr8, b2, X, N_NODES);

    // loss
    zero_float_kernel<<<1, 1, 0, stream>>>(out);
    loss_kernel<<<(BATCH + 3) / 4, 256, 0, stream>>>(X, user_id, pos_item, neg_item, out);
}

// Round 8
// 1134.144 us; speedup vs baseline: 2.4021x; 1.2246x over previous
//
#include <hip/hip_runtime.h>
#include <hip/hip_bf16.h>
#include <math.h>

#define USER_NUM 100000
#define ITEM_NUM 50000
#define N_NODES  150000
#define N_EDGES  2400000
#define OUT_DIM  64
#define HID_DIM  128
#define BATCH    4096
#define EPS_BN   1e-5f

typedef unsigned short ushort_t;
typedef unsigned int uint_t;

// fp32 -> bf16 (round-to-nearest-even), and back
__device__ __forceinline__ ushort_t f2bf(float f) {
    uint_t u = __float_as_uint(f);
    u += 0x7FFFu + ((u >> 16) & 1u);
    return (ushort_t)(u >> 16);
}
__device__ __forceinline__ float bf2f(ushort_t s) {
    return __uint_as_float((uint_t)s << 16);
}

// ---------------- preprocessing ----------------

__global__ __launch_bounds__(256) void zero_int_kernel(int* __restrict__ p, int n) {
    int i = blockIdx.x * 256 + threadIdx.x;
    if (i < n) p[i] = 0;
}

__global__ __launch_bounds__(256) void count_kernel(const int* __restrict__ dst, int* __restrict__ cnt) {
    int i = blockIdx.x * 256 + threadIdx.x;
    if (i < N_EDGES) atomicAdd(&cnt[dst[i]], 1);
}

__global__ __launch_bounds__(256) void dis_kernel(const int* __restrict__ cnt, float* __restrict__ dis) {
    int i = blockIdx.x * 256 + threadIdx.x;
    if (i < N_NODES) dis[i] = rsqrtf(1.0f + (float)cnt[i]);
}

// 3-pass scan: per-block sums -> scan of block sums -> emit offsets
#define SC_ELEM 1024
#define SC_NB   ((N_NODES + SC_ELEM - 1) / SC_ELEM)   // 147

__global__ __launch_bounds__(256) void scan_part_kernel(const int* __restrict__ cnt,
                                                        int* __restrict__ psum) {
    __shared__ int red[4];
    int tid = threadIdx.x;
    int base = blockIdx.x * SC_ELEM + tid * 4;
    int s = 0;
#pragma unroll
    for (int j = 0; j < 4; j++) { int i = base + j; if (i < N_NODES) s += cnt[i]; }
#pragma unroll
    for (int d = 1; d < 64; d <<= 1) s += __shfl_xor(s, d);
    if ((tid & 63) == 0) red[tid >> 6] = s;
    __syncthreads();
    if (tid == 0) psum[blockIdx.x] = red[0] + red[1] + red[2] + red[3];
}

__global__ __launch_bounds__(256) void scan_mid_kernel(int* __restrict__ psum,
                                                       int* __restrict__ off, int nb) {
    __shared__ int lds[256];
    int tid = threadIdx.x;
    int v = (tid < nb) ? psum[tid] : 0;
    lds[tid] = v;
    __syncthreads();
    for (int d = 1; d < 256; d <<= 1) {
        int t = (tid >= d) ? lds[tid - d] : 0;
        __syncthreads();
        lds[tid] += t;
        __syncthreads();
    }
    if (tid < nb) psum[tid] = lds[tid] - v;   // exclusive
    if (tid == 0) off[N_NODES] = lds[255];
}

__global__ __launch_bounds__(256) void scan_emit_kernel(const int* __restrict__ cnt,
                                                        const int* __restrict__ psum,
                                                        int* __restrict__ off,
                                                        int* __restrict__ cur) {
    __shared__ int lds[256];
    int tid = threadIdx.x;
    int base = blockIdx.x * SC_ELEM + tid * 4;
    int v[4]; int s = 0;
#pragma unroll
    for (int j = 0; j < 4; j++) {
        int i = base + j;
        v[j] = (i < N_NODES) ? cnt[i] : 0;
        s += v[j];
    }
    lds[tid] = s;
    __syncthreads();
    for (int d = 1; d < 256; d <<= 1) {
        int t = (tid >= d) ? lds[tid - d] : 0;
        __syncthreads();
        lds[tid] += t;
        __syncthreads();
    }
    int run = psum[blockIdx.x] + lds[tid] - s;
#pragma unroll
    for (int j = 0; j < 4; j++) {
        int i = base + j;
        if (i < N_NODES) { off[i] = run; cur[i] = run; }
        run += v[j];
    }
}

// CSR entry: .x = src node, .y = bit-pattern of edge weight dis[src]*dis[dst]
__global__ __launch_bounds__(256) void fill_kernel(const int* __restrict__ src, const int* __restrict__ dst,
                                                   const float* __restrict__ dis,
                                                   int* __restrict__ cursor,
                                                   uint2* __restrict__ csr8) {
    int i = blockIdx.x * 256 + threadIdx.x;
    if (i < N_EDGES) {
        int s = src[i];
        int d = dst[i];
        int p = atomicAdd(&cursor[d], 1);
        uint2 e;
        e.x = (uint_t)s;
        e.y = __float_as_uint(dis[s] * dis[d]);
        csr8[p] = e;
    }
}

// ---------------- GEMM: out[M][DOUT] = x[M][DIN] @ W[DIN][DOUT], bf16 output ----------------
// XT = float or ushort_t (bf16) input. 256 threads, block tile MBLK x DOUT,
// micro-tile 8x8 per thread, K-chunks of 32 in LDS with reg-staged prefetch.

__device__ __forceinline__ float4 load4(const float* p) { return *(const float4*)p; }
__device__ __forceinline__ float4 load4(const ushort_t* p) {
    ushort4 u = *(const ushort4*)p;
    return make_float4(bf2f(u.x), bf2f(u.y), bf2f(u.z), bf2f(u.w));
}

template<typename XT, int DIN, int DOUT, int MBLK>
__global__ __launch_bounds__(256) void gemm_kernel(const XT* __restrict__ xlo,
                                                   const XT* __restrict__ xhi, int split,
                                                   const float* __restrict__ W,
                                                   ushort_t* __restrict__ out, int nrows) {
    constexpr int KC    = 32;
    constexpr int NC    = DIN / KC;
    constexpr int XS_PT = MBLK / 32;      // 4-elem x-loads per thread per chunk
    constexpr int WS_PT = DOUT / 32;      // float4 w-loads per thread per chunk
    constexpr int NCOLG = DOUT / 8;

    __shared__ float xs[MBLK][KC + 1];    // +1 pad: conflict-free column reads
    __shared__ float ws[KC][DOUT];

    const int tid  = threadIdx.x;
    const int row0 = blockIdx.x * MBLK;
    const int colg = tid % NCOLG;
    const int rowg = tid / NCOLG;

    float4 xr[XS_PT], wr[WS_PT];

    auto load_chunk = [&](int kc) {
#pragma unroll
        for (int i = 0; i < XS_PT; i++) {
            int idx = i * 256 + tid;
            int m = idx >> 3, kq = idx & 7;
            int row = row0 + m; if (row > nrows - 1) row = nrows - 1;
            const XT* rp = (row < split) ? xlo + (size_t)row * DIN
                                         : xhi + (size_t)(row - split) * DIN;
            xr[i] = load4(rp + kc + kq * 4);
        }
#pragma unroll
        for (int i = 0; i < WS_PT; i++) {
            int idx = i * 256 + tid;
            int n4 = idx % (DOUT / 4), kk = idx / (DOUT / 4);
            wr[i] = *(const float4*)(W + (size_t)(kc + kk) * DOUT + n4 * 4);
        }
    };
    auto write_chunk = [&]() {
#pragma unroll
        for (int i = 0; i < XS_PT; i++) {
            int idx = i * 256 + tid;
            int m = idx >> 3, kq = idx & 7;
            xs[m][kq * 4 + 0] = xr[i].x;
            xs[m][kq * 4 + 1] = xr[i].y;
            xs[m][kq * 4 + 2] = xr[i].z;
            xs[m][kq * 4 + 3] = xr[i].w;
        }
#pragma unroll
        for (int i = 0; i < WS_PT; i++) {
            int idx = i * 256 + tid;
            int n4 = idx % (DOUT / 4), kk = idx / (DOUT / 4);
            *(float4*)&ws[kk][n4 * 4] = wr[i];
        }
    };

    float acc[8][8];
#pragma unroll
    for (int r = 0; r < 8; r++)
#pragma unroll
        for (int c = 0; c < 8; c++) acc[r][c] = 0.f;

    load_chunk(0);
    write_chunk();
    __syncthreads();

    for (int c = 0; c < NC; c++) {
        if (c + 1 < NC) load_chunk((c + 1) * KC);   // prefetch under compute
#pragma unroll 4
        for (int k = 0; k < KC; k++) {
            float4 wa = *(const float4*)&ws[k][colg * 8];
            float4 wb = *(const float4*)&ws[k][colg * 8 + 4];
            float xv[8];
#pragma unroll
            for (int r = 0; r < 8; r++) xv[r] = xs[rowg * 8 + r][k];
#pragma unroll
            for (int r = 0; r < 8; r++) {
                acc[r][0] = fmaf(xv[r], wa.x, acc[r][0]);
                acc[r][1] = fmaf(xv[r], wa.y, acc[r][1]);
                acc[r][2] = fmaf(xv[r], wa.z, acc[r][2]);
                acc[r][3] = fmaf(xv[r], wa.w, acc[r][3]);
                acc[r][4] = fmaf(xv[r], wb.x, acc[r][4]);
                acc[r][5] = fmaf(xv[r], wb.y, acc[r][5]);
                acc[r][6] = fmaf(xv[r], wb.z, acc[r][6]);
                acc[r][7] = fmaf(xv[r], wb.w, acc[r][7]);
            }
        }
        __syncthreads();
        if (c + 1 < NC) { write_chunk(); __syncthreads(); }
    }

#pragma unroll
    for (int r = 0; r < 8; r++) {
        int row = row0 + rowg * 8 + r;
        if (row < nrows) {
            uint4 pk;
            pk.x = (uint_t)f2bf(acc[r][0]) | ((uint_t)f2bf(acc[r][1]) << 16);
            pk.y = (uint_t)f2bf(acc[r][2]) | ((uint_t)f2bf(acc[r][3]) << 16);
            pk.z = (uint_t)f2bf(acc[r][4]) | ((uint_t)f2bf(acc[r][5]) << 16);
            pk.w = (uint_t)f2bf(acc[r][6]) | ((uint_t)f2bf(acc[r][7]) << 16);
            *(uint4*)&out[(size_t)row * DOUT + colg * 8] = pk;
        }
    }
}

// ---------------- edge aggregation (CSR gather over bf16 h, one wave per node) ----------------
// out[i] = sum_e w_e*h[s_e] + h[i]*dis[i]^2 + bias   (fp32 accumulate/output)

template<int DOUT>
__global__ __launch_bounds__(256) void agg_kernel(const ushort_t* __restrict__ h,
                                                  const float* __restrict__ dis,
                                                  const int* __restrict__ off,
                                                  const uint2* __restrict__ csr8,
                                                  const float* __restrict__ bias,
                                                  float* __restrict__ out, int n) {
    int wave = threadIdx.x >> 6;
    int lane = threadIdx.x & 63;
    int node = blockIdx.x * 4 + wave;
    if (node >= n) return;
    float di  = dis[node];
    int   beg = off[node], end = off[node + 1];
    if (DOUT == 128) {
        const uint_t* hp = (const uint_t*)h;   // 64 uints (128 bf16) per row
        float ax = 0.f, ay = 0.f;
        int e = beg;
        for (; e + 4 <= end; e += 4) {
            uint2 e0 = csr8[e], e1 = csr8[e + 1], e2 = csr8[e + 2], e3 = csr8[e + 3];
            uint_t u0 = hp[(size_t)e0.x * 64 + lane];
            uint_t u1 = hp[(size_t)e1.x * 64 + lane];
            uint_t u2 = hp[(size_t)e2.x * 64 + lane];
            uint_t u3 = hp[(size_t)e3.x * 64 + lane];
            float w0 = __uint_as_float(e0.y), w1 = __uint_as_float(e1.y);
            float w2 = __uint_as_float(e2.y), w3 = __uint_as_float(e3.y);
            ax = fmaf(__uint_as_float(u0 << 16), w0, ax);
            ay = fmaf(__uint_as_float(u0 & 0xFFFF0000u), w0, ay);
            ax = fmaf(__uint_as_float(u1 << 16), w1, ax);
            ay = fmaf(__uint_as_float(u1 & 0xFFFF0000u), w1, ay);
            ax = fmaf(__uint_as_float(u2 << 16), w2, ax);
            ay = fmaf(__uint_as_float(u2 & 0xFFFF0000u), w2, ay);
            ax = fmaf(__uint_as_float(u3 << 16), w3, ax);
            ay = fmaf(__uint_as_float(u3 & 0xFFFF0000u), w3, ay);
        }
        for (; e < end; e++) {
            uint2 ev = csr8[e];
            float wv = __uint_as_float(ev.y);
            uint_t u = hp[(size_t)ev.x * 64 + lane];
            ax = fmaf(__uint_as_float(u << 16), wv, ax);
            ay = fmaf(__uint_as_float(u & 0xFFFF0000u), wv, ay);
        }
        uint_t us = hp[(size_t)node * 64 + lane];
        float2 bb = ((const float2*)bias)[lane];
        float dd = di * di;
        float2 o;
        o.x = ax + __uint_as_float(us << 16) * dd + bb.x;
        o.y = ay + __uint_as_float(us & 0xFFFF0000u) * dd + bb.y;
        ((float2*)out)[(size_t)node * 64 + lane] = o;
    } else {
        float ax = 0.f;
        int e = beg;
        for (; e + 4 <= end; e += 4) {
            uint2 e0 = csr8[e], e1 = csr8[e + 1], e2 = csr8[e + 2], e3 = csr8[e + 3];
            float h0 = bf2f(h[(size_t)e0.x * 64 + lane]);
            float h1 = bf2f(h[(size_t)e1.x * 64 + lane]);
            float h2 = bf2f(h[(size_t)e2.x * 64 + lane]);
            float h3 = bf2f(h[(size_t)e3.x * 64 + lane]);
            ax = fmaf(h0, __uint_as_float(e0.y), ax);
            ax = fmaf(h1, __uint_as_float(e1.y), ax);
            ax = fmaf(h2, __uint_as_float(e2.y), ax);
            ax = fmaf(h3, __uint_as_float(e3.y), ax);
        }
        for (; e < end; e++) {
            uint2 ev = csr8[e];
            ax = fmaf(bf2f(h[(size_t)ev.x * 64 + lane]), __uint_as_float(ev.y), ax);
        }
        float hs = bf2f(h[(size_t)node * 64 + lane]);
        out[(size_t)node * 64 + lane] = ax + hs * di * di + bias[lane];
    }
}

// ---------------- BN stats (two-stage, double partials) ----------------

#define STATS_NB 512

__global__ __launch_bounds__(128) void stats1_kernel(const float* __restrict__ x,
                                                     double* __restrict__ part) {
    int col = threadIdx.x;
    double a = 0.0, b = 0.0;
    for (int row = blockIdx.x; row < N_NODES; row += STATS_NB) {
        float v = x[(size_t)row * HID_DIM + col];
        a += v;
        b += (double)v * (double)v;
    }
    part[(size_t)blockIdx.x * 256 + col]       = a;
    part[(size_t)blockIdx.x * 256 + 128 + col] = b;
}

// parallel final reduce: one block per column, 256 threads sweep the partials
__global__ __launch_bounds__(256) void stats2_kernel(const double* __restrict__ part,
                                                     const float* __restrict__ g,
                                                     const float* __restrict__ beta,
                                                     float* __restrict__ a_out,
                                                     float* __restrict__ b_out) {
    __shared__ double red1[4], red2[4];
    int col = blockIdx.x;       // 0..127
    int tid = threadIdx.x;
    double s1 = 0.0, s2 = 0.0;
    for (int p = tid; p < STATS_NB; p += 256) {
        s1 += part[(size_t)p * 256 + col];
        s2 += part[(size_t)p * 256 + 128 + col];
    }
#pragma unroll
    for (int d = 32; d >= 1; d >>= 1) {
        s1 += __shfl_xor(s1, d);
        s2 += __shfl_xor(s2, d);
    }
    int wave = tid >> 6, lane = tid & 63;
    if (lane == 0) { red1[wave] = s1; red2[wave] = s2; }
    __syncthreads();
    if (tid == 0) {
        double t1 = red1[0] + red1[1] + red1[2] + red1[3];
        double t2 = red2[0] + red2[1] + red2[2] + red2[3];
        double mean = t1 / (double)N_NODES;
        double var  = t2 / (double)N_NODES - mean * mean;
        float inv = rsqrtf((float)var + EPS_BN);
        float aa  = g[col] * inv;
        a_out[col] = aa;
        b_out[col] = beta[col] - (float)mean * aa;
    }
}

// ---------------- fused BN-apply + ReLU + row L2-norm -> bf16 (wave per row) ----------------

__global__ __launch_bounds__(256) void bn_relu_l2_kernel(const float* __restrict__ in,
                                                         const float* __restrict__ a,
                                                         const float* __restrict__ b,
                                                         uint_t* __restrict__ outp, int n) {
    int wave = threadIdx.x >> 6;
    int lane = threadIdx.x & 63;
    int row  = blockIdx.x * 4 + wave;
    if (row >= n) return;
    float2 v  = *(const float2*)(in + (size_t)row * 128 + lane * 2);
    float2 aa = *(const float2*)(a + lane * 2);
    float2 bb = *(const float2*)(b + lane * 2);
    float y0 = fmaxf(fmaf(v.x, aa.x, bb.x), 0.f);
    float y1 = fmaxf(fmaf(v.y, aa.y, bb.y), 0.f);
    float ss = y0 * y0 + y1 * y1;
#pragma unroll
    for (int d = 32; d >= 1; d >>= 1) ss += __shfl_xor(ss, d);
    float nn  = sqrtf(ss);
    float inv = 1.f / fmaxf(nn, 1e-12f);
    uint_t pk = (uint_t)f2bf(y0 * inv) | ((uint_t)f2bf(y1 * inv) << 16);
    outp[(size_t)row * 64 + lane] = pk;
}

// ---------------- loss ----------------

__global__ void zero_float_kernel(float* p) { *p = 0.f; }

__global__ __launch_bounds__(256) void loss_kernel(const float* __restrict__ X,
                                                   const int* __restrict__ uid,
                                                   const int* __restrict__ pid,
                                                   const int* __restrict__ nid,
                                                   float* __restrict__ out0) {
    int wave = threadIdx.x >> 6;
    int lane = threadIdx.x & 63;
    int b = blockIdx.x * 4 + wave;
    if (b >= BATCH) return;
    const float* u = X + (size_t)uid[b] * OUT_DIM;
    const float* p = X + (size_t)(USER_NUM + pid[b]) * OUT_DIM;
    const float* q = X + (size_t)(USER_NUM + nid[b]) * OUT_DIM;
    float uv = u[lane];
    float ps = uv * p[lane];
    float ns = uv * q[lane];
#pragma unroll
    for (int d = 32; d >= 1; d >>= 1) {
        ps += __shfl_xor(ps, d);
        ns += __shfl_xor(ns, d);
    }
    if (lane == 0) {
        float t  = ns - ps;                                   // -(pos - neg)
        float sp = fmaxf(t, 0.f) + log1pf(expf(-fabsf(t)));   // softplus(t)
        atomicAdd(out0, sp * (1.0f / BATCH));
    }
}

// ---------------- launch ----------------

extern "C" void kernel_launch(void* const* d_in, const int* in_sizes, int n_in,
                              void* d_out, int out_size, void* d_ws, size_t ws_size,
                              hipStream_t stream) {
    const float* user_emb = (const float*)d_in[0];
    const float* item_emb = (const float*)d_in[1];
    const float* W0  = (const float*)d_in[2];
    const float* b0  = (const float*)d_in[3];
    const float* g0  = (const float*)d_in[4];
    const float* be0 = (const float*)d_in[5];
    const float* W1  = (const float*)d_in[6];
    const float* b1  = (const float*)d_in[7];
    const float* g1  = (const float*)d_in[8];
    const float* be1 = (const float*)d_in[9];
    const float* W2  = (const float*)d_in[10];
    const float* b2  = (const float*)d_in[11];
    const int* user_id  = (const int*)d_in[12];
    const int* pos_item = (const int*)d_in[13];
    const int* neg_item = (const int*)d_in[14];
    const int* edge     = (const int*)d_in[15];
    const int* src = edge;
    const int* dst = edge + N_EDGES;

    char* w = (char*)d_ws;
    auto alloc = [&](size_t bytes) -> char* {
        char* r = w;
        w += (bytes + 255) / 256 * 256;
        return r;
    };
    int*      cnt  = (int*)alloc((size_t)N_NODES * 4);
    int*      off  = (int*)alloc((size_t)(N_NODES + 1) * 4);
    int*      cur  = (int*)alloc((size_t)N_NODES * 4);
    uint2*    csr8 = (uint2*)alloc((size_t)N_EDGES * 8);
    float*    dis  = (float*)alloc((size_t)N_NODES * 4);
    int*      psum = (int*)alloc((size_t)SC_NB * 4);
    double*   part = (double*)alloc((size_t)STATS_NB * 256 * 8);
    float*    bn_a = (float*)alloc(128 * 4);
    float*    bn_b = (float*)alloc(128 * 4);
    ushort_t* hbuf = (ushort_t*)alloc((size_t)N_NODES * HID_DIM * 2);   // bf16 GEMM output
    float*    xbuf = (float*)alloc((size_t)N_NODES * HID_DIM * 4);      // fp32 agg output
    ushort_t* xbf  = (ushort_t*)alloc((size_t)N_NODES * HID_DIM * 2);   // bf16 normalized x

    float* out = (float*)d_out;
    float* X   = out + 1;   // node embeddings region (150000 x 64)

    const int EB = (N_EDGES + 255) / 256;
    const int NB = (N_NODES + 255) / 256;
    const int AGGB = (N_NODES + 3) / 4;

    // preprocessing: degree, dis, CSR (+ fused per-edge weights)
    zero_int_kernel<<<NB, 256, 0, stream>>>(cnt, N_NODES);
    count_kernel<<<EB, 256, 0, stream>>>(dst, cnt);
    dis_kernel<<<NB, 256, 0, stream>>>(cnt, dis);
    scan_part_kernel<<<SC_NB, 256, 0, stream>>>(cnt, psum);
    scan_mid_kernel<<<1, 256, 0, stream>>>(psum, off, SC_NB);
    scan_emit_kernel<<<SC_NB, 256, 0, stream>>>(cnt, psum, off, cur);
    fill_kernel<<<EB, 256, 0, stream>>>(src, dst, dis, cur, csr8);

    // layer 0: (150000x64 fp32) @ (64x128)
    gemm_kernel<float, 64, 128, 128><<<(N_NODES + 127) / 128, 256, 0, stream>>>(
        user_emb, item_emb, USER_NUM, W0, hbuf, N_NODES);
    agg_kernel<128><<<AGGB, 256, 0, stream>>>(hbuf, dis, off, csr8, b0, xbuf, N_NODES);
    stats1_kernel<<<STATS_NB, 128, 0, stream>>>(xbuf, part);
    stats2_kernel<<<128, 256, 0, stream>>>(part, g0, be0, bn_a, bn_b);
    bn_relu_l2_kernel<<<AGGB, 256, 0, stream>>>(xbuf, bn_a, bn_b, (uint_t*)xbf, N_NODES);

    // layer 1: (150000x128 bf16) @ (128x128)
    gemm_kernel<ushort_t, 128, 128, 128><<<(N_NODES + 127) / 128, 256, 0, stream>>>(
        xbf, xbf, N_NODES, W1, hbuf, N_NODES);
    agg_kernel<128><<<AGGB, 256, 0, stream>>>(hbuf, dis, off, csr8, b1, xbuf, N_NODES);
    stats1_kernel<<<STATS_NB, 128, 0, stream>>>(xbuf, part);
    stats2_kernel<<<128, 256, 0, stream>>>(part, g1, be1, bn_a, bn_b);
    bn_relu_l2_kernel<<<AGGB, 256, 0, stream>>>(xbuf, bn_a, bn_b, (uint_t*)xbf, N_NODES);

    // layer 2: (150000x128 bf16) @ (128x64)
    gemm_kernel<ushort_t, 128, 64, 256><<<(N_NODES + 255) / 256, 256, 0, stream>>>(
        xbf, xbf, N_NODES, W2, hbuf, N_NODES);
    agg_kernel<64><<<AGGB, 256, 0, stream>>>(hbuf, dis, off, csr8, b2, X, N_NODES);

    // loss
    zero_float_kernel<<<1, 1, 0, stream>>>(out);
    loss_kernel<<<(BATCH + 3) / 4, 256, 0, stream>>>(X, user_id, pos_item, neg_item, out);
}